// Round 1
// baseline (456.518 us; speedup 1.0000x reference)
//
#include <hip/hip_runtime.h>
#include <math.h>
#include <type_traits>

// Problem constants (fixed by reference)
#define KD 128      // K dim of every GEMM (IN = HC = 128)
#define HC 128      // H*C for layers 0/1
#define NF2 188     // H*OUT for layer 2
#define NF2PB 192   // padded layer-2 row stride in BYTES (fp8: 3 cachelines)
#define OUTC 47

typedef __attribute__((ext_vector_type(8))) __bf16 bf16x8;
typedef __attribute__((ext_vector_type(4))) float f32x4;
typedef __attribute__((ext_vector_type(2))) float f32x2;

#ifdef __has_builtin
#if __has_builtin(__builtin_amdgcn_cvt_pk_f32_fp8)
#define HAVE_CVT_FP8_DEC 1
#endif
#if __has_builtin(__builtin_amdgcn_cvt_pk_fp8_f32)
#define HAVE_CVT_FP8_ENC 1
#endif
#endif

__device__ inline float bfhi_to_f(unsigned int u) {
    union { unsigned int u; float f; } c; c.u = u & 0xFFFF0000u; return c.f;
}
__device__ inline float bflo_to_f(unsigned int u) {
    union { unsigned int u; float f; } c; c.u = u << 16; return c.f;
}
__device__ inline unsigned short f_to_bfu(float f) {
    return __builtin_bit_cast(unsigned short, (__bf16)f);
}
__device__ inline unsigned int pk_bf(float a, float b) {
    return (unsigned int)f_to_bfu(a) | ((unsigned int)f_to_bfu(b) << 16);
}

// acc += x.lo*a.lo + x.hi*a.hi  (bf16 pairs, f32 accumulate) — VOP3P
__device__ inline void dot2bf(float& acc, unsigned int x, unsigned int a) {
    asm("v_dot2_f32_bf16 %0, %1, %2, %0" : "+v"(acc) : "v"(x), "v"(a));
}
// byte-select: result = bytes of (hi:lo) picked by sel
__device__ inline unsigned int permb(unsigned int hi, unsigned int lo, unsigned int sel) {
    return __builtin_amdgcn_perm(hi, lo, sel);
}

// ---- fp8 e4m3 helpers (HW cvt on gfx950; bit-math fallback) ----
#ifndef HAVE_CVT_FP8_DEC
__device__ inline float fp8_to_f32_b(unsigned int b) {
    int e = (b >> 3) & 15, m = b & 7;
    float v = e ? ldexpf((float)(8 + m), e - 10) : ldexpf((float)m, -9);
    return (b & 0x80) ? -v : v;
}
#endif
__device__ inline void fp8x4_dec(unsigned int q, float& a, float& b, float& c, float& d) {
#ifdef HAVE_CVT_FP8_DEC
    f32x2 lo = __builtin_amdgcn_cvt_pk_f32_fp8((int)q, false);
    f32x2 hi = __builtin_amdgcn_cvt_pk_f32_fp8((int)q, true);
    a = lo[0]; b = lo[1]; c = hi[0]; d = hi[1];
#else
    a = fp8_to_f32_b(q & 0xFF); b = fp8_to_f32_b((q >> 8) & 0xFF);
    c = fp8_to_f32_b((q >> 16) & 0xFF); d = fp8_to_f32_b((q >> 24) & 0xFF);
#endif
}
__device__ inline unsigned char f32_to_fp8(float v) {
#ifdef HAVE_CVT_FP8_ENC
    return (unsigned char)(__builtin_amdgcn_cvt_pk_fp8_f32(v, v, 0, false) & 0xFF);
#else
    unsigned u = __builtin_bit_cast(unsigned, v);
    unsigned s = (u >> 24) & 0x80;
    float a = fabsf(v);
    if (a < 0.0009765625f) return (unsigned char)s;
    if (a >= 448.f) return (unsigned char)(s | 0x7E);
    int e; float m = frexpf(a, &e);        // a = m*2^e, m in [0.5,1)
    int E = e - 1 + 7;
    int mi = (int)rintf(m * 16.f);         // in [8,16]
    if (mi == 16) { mi = 8; ++E; if (E >= 16) return (unsigned char)(s | 0x7E); }
    if (E <= 0) {
        int q = (int)rintf(a * 512.f); if (q > 7) q = 7;
        return (unsigned char)(s | q);
    }
    return (unsigned char)(s | (E << 3) | (mi - 8));
#endif
}
// acc += dot(4 fp8 of q, al)
__device__ inline float fp8dot(unsigned int q, float4 al, float acc) {
    float a, b, c, d;
    fp8x4_dec(q, a, b, c, d);
    return acc + al.x * a + al.y * b + al.z * c + al.w * d;
}

// ---------------------------------------------------------------------------
// CSR build: memset(deg,counter) -> count -> scan(+selfloop,+writeback) -> fill
// 8 edges/thread (measured optimum — R10 post-mortem).
// ---------------------------------------------------------------------------
__global__ void count_kernel(const int* __restrict__ dst, int* deg, int e) {
    int t = blockIdx.x * blockDim.x + threadIdx.x;
    int base = t * 8;
    if (base + 7 < e) {
        int4 d0 = *(const int4*)(dst + base);
        int4 d1 = *(const int4*)(dst + base + 4);
        atomicAdd(&deg[d0.x], 1); atomicAdd(&deg[d0.y], 1);
        atomicAdd(&deg[d0.z], 1); atomicAdd(&deg[d0.w], 1);
        atomicAdd(&deg[d1.x], 1); atomicAdd(&deg[d1.y], 1);
        atomicAdd(&deg[d1.z], 1); atomicAdd(&deg[d1.w], 1);
    } else {
        for (int k = base; k < e; ++k) atomicAdd(&deg[dst[k]], 1);
    }
}

__global__ __launch_bounds__(256) void scan_base_kernel(
    int* __restrict__ deg, int* counter,
    int* __restrict__ row_ptr, int* __restrict__ fill, int* __restrict__ col, int n) {
    int i = blockIdx.x * 256 + threadIdx.x;
    int v = (i < n) ? (deg[i] + 1) : 0;
    int lane = threadIdx.x & 63, w = threadIdx.x >> 6;
    int incl = v;
#pragma unroll
    for (int off = 1; off < 64; off <<= 1) {
        int u = __shfl_up(incl, off, 64);
        if (lane >= off) incl += u;
    }
    __shared__ int wsum[4];
    __shared__ int base_sh;
    if (lane == 63) wsum[w] = incl;
    __syncthreads();
    if (threadIdx.x == 0)
        base_sh = atomicAdd(counter, wsum[0] + wsum[1] + wsum[2] + wsum[3]);
    int woff = 0;
    for (int k = 0; k < w; ++k) woff += wsum[k];
    __syncthreads();
    int excl = base_sh + woff + incl - v;
    if (i < n) {
        row_ptr[i] = excl;
        col[excl] = i;        // self-loop at segment head
        fill[i] = excl + 1;   // edges fill after it
        deg[i] = v;           // write back incl. self-loop
    }
}

__global__ void fill_kernel(const int* __restrict__ ei, int* fill, int* col, int e) {
    int t = blockIdx.x * blockDim.x + threadIdx.x;
    int base = t * 8;
    if (base + 7 < e) {
        int4 s0 = *(const int4*)(ei + base);
        int4 s1 = *(const int4*)(ei + base + 4);
        int4 d0 = *(const int4*)(ei + e + base);
        int4 d1 = *(const int4*)(ei + e + base + 4);
        int p0 = atomicAdd(&fill[d0.x], 1);
        int p1 = atomicAdd(&fill[d0.y], 1);
        int p2 = atomicAdd(&fill[d0.z], 1);
        int p3 = atomicAdd(&fill[d0.w], 1);
        int p4 = atomicAdd(&fill[d1.x], 1);
        int p5 = atomicAdd(&fill[d1.y], 1);
        int p6 = atomicAdd(&fill[d1.z], 1);
        int p7 = atomicAdd(&fill[d1.w], 1);
        col[p0] = s0.x; col[p1] = s0.y; col[p2] = s0.z; col[p3] = s0.w;
        col[p4] = s1.x; col[p5] = s1.y; col[p6] = s1.z; col[p7] = s1.w;
    } else {
        for (int k = base; k < e; ++k) {
            int pos = atomicAdd(&fill[ei[e + k]], 1);
            col[pos] = ei[k];
        }
    }
}

// ---------------------------------------------------------------------------
// One-shot weight prep: transpose + convert all 6 weight matrices into padded
// bf16 [n][k] buffers (64-row-aligned tiles, zero rows past true N).
//   Bt layout per layer L (256 rows x 128 k):
//     L0/L1: rows 0..127 = lin_w^T, 128..255 = skip_w^T
//     L2:    rows 0..187 = lin_w2^T, 188..191 = 0, 192..238 = skip_w2^T, rest 0
// ---------------------------------------------------------------------------
__global__ __launch_bounds__(256) void prep_w_kernel(
    const float* __restrict__ lw0, const float* __restrict__ sw0,
    const float* __restrict__ lw1, const float* __restrict__ sw1,
    const float* __restrict__ lw2, const float* __restrict__ sw2,
    __bf16* __restrict__ bt) {
    int idx = blockIdx.x * 256 + threadIdx.x;   // 3 * 256 * 128 = 98304 total
    int buf = idx >> 15;                        // / 32768
    int r = idx & 32767;
    int n = r >> 7, k = r & 127;
    float v = 0.f;
    if (buf == 0) v = (n < 128) ? lw0[k * 128 + n] : sw0[k * 128 + n - 128];
    else if (buf == 1) v = (n < 128) ? lw1[k * 128 + n] : sw1[k * 128 + n - 128];
    else {
        if (n < 188) v = lw2[k * 188 + n];
        else if (n >= 192 && n < 239) v = sw2[k * 47 + n - 192];
    }
    bt[idx] = (__bf16)v;
}

// ---------------------------------------------------------------------------
// Fused bf16 MFMA GEMM: A staged ONCE per block (BM=64) in LDS; B fragments
// read DIRECTLY from the prepped bf16 [n][k] buffer (L2-resident, no LDS
// staging, no per-tile barriers). Loop over all column tiles in-kernel:
//   tiles [0, NLIN)        : out0 = A @ lin
//       TR=0: bf16 store, elem stride ldc0
//       TR=1: fp8 e4m3 store, head-interleaved (byte idx = row*ldc0 + oc*4+h)
//   tiles [NLIN, NLIN+NSK) : out1 = A @ skip + bias1 (SKT store)
// ---------------------------------------------------------------------------
template <typename AT, typename SKT, int NLIN, int NSK, int TR>
__global__ __launch_bounds__(256) void gemm_fused_kernel(
    const AT* __restrict__ A, const __bf16* __restrict__ Bt,
    void* __restrict__ out0, int N0, int ldc0,
    const float* __restrict__ bias1, SKT* __restrict__ out1, int N1, int M) {
    __shared__ __bf16 As[64][136];    // [m][k], +8 pad (16B-aligned rows)
    int tid = threadIdx.x;
    int m0 = blockIdx.x * 64;

    // stage A: 64 rows x 128 elems, 16B LDS writes (read once!)
#pragma unroll
    for (int rep = 0; rep < 4; ++rep) {
        int idx = tid + rep * 256;          // 0..1023
        int row = idx >> 4, seg = idx & 15; // 8-elem segment within row
        int gm = m0 + row;
        bf16x8 v = {};
        if (gm < M) {
            if constexpr (std::is_same<AT, float>::value) {
                const float* p = A + gm * KD + seg * 8;
                float4 f0 = *(const float4*)p;
                float4 f1 = *(const float4*)(p + 4);
                v[0] = (__bf16)f0.x; v[1] = (__bf16)f0.y; v[2] = (__bf16)f0.z; v[3] = (__bf16)f0.w;
                v[4] = (__bf16)f1.x; v[5] = (__bf16)f1.y; v[6] = (__bf16)f1.z; v[7] = (__bf16)f1.w;
            } else {
                v = *(const bf16x8*)(A + gm * KD + seg * 8);
            }
        }
        *(bf16x8*)&As[row][seg * 8] = v;
    }
    __syncthreads();

    int w = tid >> 6, lane = tid & 63;
    int lr = lane & 15, quad = lane >> 4;

#pragma unroll
    for (int t = 0; t < NLIN + NSK; ++t) {
        bool second = t >= NLIN;
        int N = second ? N1 : N0;
        int n0 = (second ? (t - NLIN) : t) * 64;
        // B fragment base: row (t*64 + c*16 + lr), contiguous in k
        const __bf16* bbase = Bt + ((t * 64 + lr) << 7) + quad * 8;

        f32x4 acc[4] = {};
#pragma unroll
        for (int kc = 0; kc < 128; kc += 32) {
            bf16x8 a0 = *(const bf16x8*)&As[w * 16 + lr][kc + quad * 8];
            bf16x8 b0 = *(const bf16x8*)(bbase + kc);
            bf16x8 b1 = *(const bf16x8*)(bbase + (16 << 7) + kc);
            bf16x8 b2 = *(const bf16x8*)(bbase + (32 << 7) + kc);
            bf16x8 b3 = *(const bf16x8*)(bbase + (48 << 7) + kc);
            acc[0] = __builtin_amdgcn_mfma_f32_16x16x32_bf16(a0, b0, acc[0], 0, 0, 0);
            acc[1] = __builtin_amdgcn_mfma_f32_16x16x32_bf16(a0, b1, acc[1], 0, 0, 0);
            acc[2] = __builtin_amdgcn_mfma_f32_16x16x32_bf16(a0, b2, acc[2], 0, 0, 0);
            acc[3] = __builtin_amdgcn_mfma_f32_16x16x32_bf16(a0, b3, acc[3], 0, 0, 0);
        }
        // epilogue: C/D layout col=lane&15, row=quad*4+reg
#pragma unroll
        for (int c = 0; c < 4; ++c) {
#pragma unroll
            for (int reg = 0; reg < 4; ++reg) {
                int row = m0 + w * 16 + quad * 4 + reg;
                int colg = n0 + c * 16 + lr;
                if (row < M && colg < N) {
                    float v = acc[c][reg];
                    if (second) {
                        v += bias1[colg];
                        out1[row * N + colg] = (SKT)v;
                    } else if (TR) {   // fp8, head-interleaved: byte = oc*4 + h
                        int h = (colg * 1395) >> 16;   // colg / 47 for colg<188
                        ((unsigned char*)out0)[row * ldc0 + (colg - 47 * h) * 4 + h] =
                            f32_to_fp8(v);
                    } else {
                        ((__bf16*)out0)[row * ldc0 + colg] = (__bf16)v;
                    }
                }
            }
        }
    }
}

// ---------------------------------------------------------------------------
// att for layers 0/1: 16 lanes per node (4 nodes/wave). Lane owns 8 feats =
// one head-quarter (head = l16>>2) -> single accumulator; 2-round reduce.
// ---------------------------------------------------------------------------
__global__ __launch_bounds__(256) void att_kernel(
    const __bf16* __restrict__ xh, const float* __restrict__ att_s,
    const float* __restrict__ att_d, float* __restrict__ a_src,
    float* __restrict__ a_dst, int n) {
    int tid = blockIdx.x * 256 + threadIdx.x;
    int node = tid >> 4;
    int l16 = threadIdx.x & 15;
    if (node >= n) return;
    uint4 q = ((const uint4*)xh)[node * 16 + l16];   // 8 bf16 feats
    int f0 = l16 * 8;
    float4 as0 = *(const float4*)(att_s + f0);
    float4 as1 = *(const float4*)(att_s + f0 + 4);
    float4 ad0 = *(const float4*)(att_d + f0);
    float4 ad1 = *(const float4*)(att_d + f0 + 4);
    float x0 = bflo_to_f(q.x), x1 = bfhi_to_f(q.x);
    float x2 = bflo_to_f(q.y), x3 = bfhi_to_f(q.y);
    float x4 = bflo_to_f(q.z), x5 = bfhi_to_f(q.z);
    float x6 = bflo_to_f(q.w), x7 = bfhi_to_f(q.w);
    float hs = x0 * as0.x + x1 * as0.y + x2 * as0.z + x3 * as0.w
             + x4 * as1.x + x5 * as1.y + x6 * as1.z + x7 * as1.w;
    float hd = x0 * ad0.x + x1 * ad0.y + x2 * ad0.z + x3 * ad0.w
             + x4 * ad1.x + x5 * ad1.y + x6 * ad1.z + x7 * ad1.w;
    hs += __shfl_xor(hs, 1, 64); hs += __shfl_xor(hs, 2, 64);
    hd += __shfl_xor(hd, 1, 64); hd += __shfl_xor(hd, 2, 64);
    if ((l16 & 3) == 0) {
        int h = l16 >> 2;
        a_src[node * 4 + h] = hs;
        a_dst[node * 4 + h] = hd;
    }
}

// ---------------------------------------------------------------------------
// att for layer 2 (fp8 head-interleaved xh, 192 B rows): lane<47 loads one
// uint = 4 heads of channel c=lane; per-head partials; 6-round butterfly.
// ---------------------------------------------------------------------------
__global__ __launch_bounds__(256) void att2_kernel(
    const unsigned char* __restrict__ xh8, const float* __restrict__ att_s,
    const float* __restrict__ att_d, float* __restrict__ a_src,
    float* __restrict__ a_dst, int n) {
    int node = (blockIdx.x * 256 + threadIdx.x) >> 6;
    int lane = threadIdx.x & 63;
    if (node >= n) return;
    float ps0 = 0.f, ps1 = 0.f, ps2 = 0.f, ps3 = 0.f;
    float pd0 = 0.f, pd1 = 0.f, pd2 = 0.f, pd3 = 0.f;
    if (lane < 47) {
        unsigned int q = ((const unsigned int*)(xh8 + node * NF2PB))[lane];
        float x0, x1, x2, x3;
        fp8x4_dec(q, x0, x1, x2, x3);
        ps0 = x0 * att_s[lane];       ps1 = x1 * att_s[47 + lane];
        ps2 = x2 * att_s[94 + lane];  ps3 = x3 * att_s[141 + lane];
        pd0 = x0 * att_d[lane];       pd1 = x1 * att_d[47 + lane];
        pd2 = x2 * att_d[94 + lane];  pd3 = x3 * att_d[141 + lane];
    }
#pragma unroll
    for (int off = 1; off <= 32; off <<= 1) {
        ps0 += __shfl_xor(ps0, off, 64); ps1 += __shfl_xor(ps1, off, 64);
        ps2 += __shfl_xor(ps2, off, 64); ps3 += __shfl_xor(ps3, off, 64);
        pd0 += __shfl_xor(pd0, off, 64); pd1 += __shfl_xor(pd1, off, 64);
        pd2 += __shfl_xor(pd2, off, 64); pd3 += __shfl_xor(pd3, off, 64);
    }
    if (lane < 4) {
        float vs = (lane == 0) ? ps0 : (lane == 1) ? ps1 : (lane == 2) ? ps2 : ps3;
        float vd = (lane == 0) ? pd0 : (lane == 1) ? pd1 : (lane == 2) ? pd2 : pd3;
        a_src[node * 4 + lane] = vs;
        a_dst[node * 4 + lane] = vd;
    }
}

// ---------------------------------------------------------------------------
// Aggregation: one wave per destination node. 32-bit indexing.
// No-max softmax (logits O(1-10); fp32 exp safe) — verified R10.
// MODE 0 (bf16 xh, 128 feats): half-wave per EDGE PAIR; lane fl owns feats
//   4fl..4fl+3. v_perm builds same-feat bf16 pairs from the two edges,
//   v_dot2_f32_bf16 with packed bf16 alpha-pair does 2 products/instr.
//   skip bf16, out bf16+ELU.
// MODE 1 (fp8 xh, 192 B rows, head-interleaved): lane c<47 loads uint =
//   4 heads of channel c; fp32 alphas; fp8dot. skip fp32, out fp32.
// ---------------------------------------------------------------------------
template <int MODE>
__global__ __launch_bounds__(256) void agg_kernel(
    const void* __restrict__ xhp, const float* __restrict__ a_src,
    const float* __restrict__ a_dst, const void* __restrict__ skipp,
    const float* __restrict__ bias, const int* __restrict__ row_ptr,
    const int* __restrict__ deg, const int* __restrict__ col,
    void* __restrict__ outp, int n) {
    __shared__ float s_af[4][64][4];      // MODE 1: f32 alphas
    __shared__ unsigned s_ap[4][32][4];   // MODE 0: packed bf16 alpha pairs [pair][head]
    __shared__ int s_j[4][64];
    int w = threadIdx.x >> 6;
    int lane = threadIdx.x & 63;
    int node = (blockIdx.x << 2) + w;
    bool active = node < n;
    int node_c = active ? node : 0;
    int start = row_ptr[node_c];
    int end = start + (active ? deg[node_c] : 0);
    float4 ad4 = *(const float4*)(a_dst + 4 * node_c);
    float adh[4] = {ad4.x, ad4.y, ad4.z, ad4.w};

    // ---- pass A: sum of exp per head (+ chunk-0 exp capture) ----
    int e0 = start + lane;
    bool ok0 = e0 < end;
    int jcap = ok0 ? col[e0] : 0;
    float evc[4];   // exp(leaky(e)) for this lane's chunk-0 edge
    {
        float4 as4 = *(const float4*)(a_src + 4 * jcap);
        float v0 = as4.x + adh[0]; v0 = v0 > 0.f ? v0 : 0.2f * v0;
        float v1 = as4.y + adh[1]; v1 = v1 > 0.f ? v1 : 0.2f * v1;
        float v2 = as4.z + adh[2]; v2 = v2 > 0.f ? v2 : 0.2f * v2;
        float v3 = as4.w + adh[3]; v3 = v3 > 0.f ? v3 : 0.2f * v3;
        evc[0] = ok0 ? __expf(v0) : 0.f;
        evc[1] = ok0 ? __expf(v1) : 0.f;
        evc[2] = ok0 ? __expf(v2) : 0.f;
        evc[3] = ok0 ? __expf(v3) : 0.f;
    }
    float s[4] = {evc[0], evc[1], evc[2], evc[3]};
    for (int e = e0 + 64; e < end; e += 64) {
        int j = col[e];
        float4 as4 = *(const float4*)(a_src + 4 * j);
        float ev[4] = {as4.x + adh[0], as4.y + adh[1], as4.z + adh[2], as4.w + adh[3]};
#pragma unroll
        for (int h = 0; h < 4; ++h) {
            float v = ev[h] > 0.f ? ev[h] : 0.2f * ev[h];
            s[h] += __expf(v);
        }
    }
#pragma unroll
    for (int off = 32; off >= 1; off >>= 1)
#pragma unroll
        for (int h = 0; h < 4; ++h) s[h] += __shfl_xor(s[h], off, 64);
    float inv[4];
#pragma unroll
    for (int h = 0; h < 4; ++h) inv[h] = 1.f / (s[h] + 1e-16f);

    // ---- pass B bookkeeping ----
    int half = lane >> 5, fl = lane & 31, myh2 = fl >> 3;
    bool lv = lane < 47;  // MODE 1 active lanes (channel c = lane)
    float acc0 = 0.f, acc1 = 0.f, acc2 = 0.f, acc3 = 0.f;
    const uint2* xb2 = (const uint2*)xhp;           // MODE 0
    const unsigned int* x8 = (const unsigned int*)xhp;  // MODE 1 (48 uints/row)

    auto run_chunk = [&](int cnt) {
        if constexpr (MODE == 0) {
            // edge-pair loop: half h walks pairs h, h+2, h+4, ...
            int npair = (cnt + 1) >> 1;
            int p = half;
            for (; p + 2 < npair; p += 4) {
                int2 j0 = *(const int2*)&s_j[w][2 * p];
                int2 j1 = *(const int2*)&s_j[w][2 * p + 4];
                unsigned ap0 = s_ap[w][p][myh2];
                unsigned ap1 = s_ap[w][p + 2][myh2];
                uint2 qa0 = xb2[(j0.x << 5) + fl];
                uint2 qb0 = xb2[(j0.y << 5) + fl];
                uint2 qa1 = xb2[(j1.x << 5) + fl];
                uint2 qb1 = xb2[(j1.y << 5) + fl];
                dot2bf(acc0, permb(qb0.x, qa0.x, 0x05040100u), ap0);
                dot2bf(acc1, permb(qb0.x, qa0.x, 0x07060302u), ap0);
                dot2bf(acc2, permb(qb0.y, qa0.y, 0x05040100u), ap0);
                dot2bf(acc3, permb(qb0.y, qa0.y, 0x07060302u), ap0);
                dot2bf(acc0, permb(qb1.x, qa1.x, 0x05040100u), ap1);
                dot2bf(acc1, permb(qb1.x, qa1.x, 0x07060302u), ap1);
                dot2bf(acc2, permb(qb1.y, qa1.y, 0x05040100u), ap1);
                dot2bf(acc3, permb(qb1.y, qa1.y, 0x07060302u), ap1);
            }
            for (; p < npair; p += 2) {
                int2 j0 = *(const int2*)&s_j[w][2 * p];
                unsigned ap0 = s_ap[w][p][myh2];
                uint2 qa0 = xb2[(j0.x << 5) + fl];
                uint2 qb0 = xb2[(j0.y << 5) + fl];
                dot2bf(acc0, permb(qb0.x, qa0.x, 0x05040100u), ap0);
                dot2bf(acc1, permb(qb0.x, qa0.x, 0x07060302u), ap0);
                dot2bf(acc2, permb(qb0.y, qa0.y, 0x05040100u), ap0);
                dot2bf(acc3, permb(qb0.y, qa0.y, 0x07060302u), ap0);
            }
        } else {
            int t = 0;
            for (; t + 7 < cnt; t += 8) {
                unsigned int q0 = lv ? x8[s_j[w][t] * 48 + lane] : 0u;
                unsigned int q1 = lv ? x8[s_j[w][t + 1] * 48 + lane] : 0u;
                unsigned int q2 = lv ? x8[s_j[w][t + 2] * 48 + lane] : 0u;
                unsigned int q3 = lv ? x8[s_j[w][t + 3] * 48 + lane] : 0u;
                unsigned int q4 = lv ? x8[s_j[w][t + 4] * 48 + lane] : 0u;
                unsigned int q5 = lv ? x8[s_j[w][t + 5] * 48 + lane] : 0u;
                unsigned int q6 = lv ? x8[s_j[w][t + 6] * 48 + lane] : 0u;
                unsigned int q7 = lv ? x8[s_j[w][t + 7] * 48 + lane] : 0u;
                acc0 = fp8dot(q0, *(const float4*)&s_af[w][t][0], acc0);
                acc0 = fp8dot(q1, *(const float4*)&s_af[w][t + 1][0], acc0);
                acc0 = fp8dot(q2, *(const float4*)&s_af[w][t + 2][0], acc0);
                acc0 = fp8dot(q3, *(const float4*)&s_af[w][t + 3][0], acc0);
                acc0 = fp8dot(q4, *(const float4*)&s_af[w][t + 4][0], acc0);
                acc0 = fp8dot(q5, *(const float4*)&s_af[w][t + 5][0], acc0);
                acc0 = fp8dot(q6, *(const float4*)&s_af[w][t + 6][0], acc0);
                acc0 = fp8dot(q7, *(const float4*)&s_af[w][t + 7][0], acc0);
            }
            for (; t + 3 < cnt; t += 4) {
                unsigned int q0 = lv ? x8[s_j[w][t] * 48 + lane] : 0u;
                unsigned int q1 = lv ? x8[s_j[w][t + 1] * 48 + lane] : 0u;
                unsigned int q2 = lv ? x8[s_j[w][t + 2] * 48 + lane] : 0u;
                unsigned int q3 = lv ? x8[s_j[w][t + 3] * 48 + lane] : 0u;
                acc0 = fp8dot(q0, *(const float4*)&s_af[w][t][0], acc0);
                acc0 = fp8dot(q1, *(const float4*)&s_af[w][t + 1][0], acc0);
                acc0 = fp8dot(q2, *(const float4*)&s_af[w][t + 2][0], acc0);
                acc0 = fp8dot(q3, *(const float4*)&s_af[w][t + 3][0], acc0);
            }
            for (; t < cnt; ++t) {
                unsigned int q = lv ? x8[s_j[w][t] * 48 + lane] : 0u;
                acc0 = fp8dot(q, *(const float4*)&s_af[w][t][0], acc0);
            }
        }
    };

    // chunk 0: reuse captured exp values, no col/a_src reload
    {
        float al[4];
#pragma unroll
        for (int h = 0; h < 4; ++h) al[h] = evc[h] * inv[h];
        s_j[w][lane] = jcap;
        if constexpr (MODE == 0) {
            float o0 = __shfl_xor(al[0], 1, 64);
            float o1 = __shfl_xor(al[1], 1, 64);
            float o2 = __shfl_xor(al[2], 1, 64);
            float o3 = __shfl_xor(al[3], 1, 64);
            if (!(lane & 1)) {
                uint4 pk = make_uint4(pk_bf(al[0], o0), pk_bf(al[1], o1),
                                      pk_bf(al[2], o2), pk_bf(al[3], o3));
                *(uint4*)&s_ap[w][lane >> 1][0] = pk;
            }
        } else {
            *(float4*)&s_af[w][lane][0] = make_float4(al[0], al[1], al[2], al[3]);
        }
        int cnt = end - start; if (cnt > 64) cnt = 64;
        run_chunk(cnt);
    }
    // remaining chunks (deg > 64: rare)
    for (int base = start + 64; base < end; base += 64) {
        int e = base + lane;
        bool ok = e < end;
        int jv = ok ? col[e] : 0;
        float4 as4 = *(const float4*)(a_src + 4 * jv);
        float asv[4] = {as4.x, as4.y, as4.z, as4.w};
        float al[4];
#pragma unroll
        for (int h = 0; h < 4; ++h) {
            float ev = asv[h] + adh[h];
            ev = ev > 0.f ? ev : 0.2f * ev;
            al[h] = ok ? __expf(ev) * inv[h] : 0.f;
        }
        s_j[w][lane] = jv;
        if constexpr (MODE == 0) {
            float o0 = __shfl_xor(al[0], 1, 64);
            float o1 = __shfl_xor(al[1], 1, 64);
            float o2 = __shfl_xor(al[2], 1, 64);
            float o3 = __shfl_xor(al[3], 1, 64);
            if (!(lane & 1)) {
                uint4 pk = make_uint4(pk_bf(al[0], o0), pk_bf(al[1], o1),
                                      pk_bf(al[2], o2), pk_bf(al[3], o3));
                *(uint4*)&s_ap[w][lane >> 1][0] = pk;
            }
        } else {
            *(float4*)&s_af[w][lane][0] = make_float4(al[0], al[1], al[2], al[3]);
        }
        int cnt = end - base; if (cnt > 64) cnt = 64;
        run_chunk(cnt);
    }

    if constexpr (MODE == 0) {
        // combine half-waves (each half accumulated its own pair subset)
        acc0 += __shfl_xor(acc0, 32, 64);
        acc1 += __shfl_xor(acc1, 32, 64);
        acc2 += __shfl_xor(acc2, 32, 64);
        acc3 += __shfl_xor(acc3, 32, 64);
        if (active && half == 0) {
            float4 bb = *(const float4*)(bias + 4 * fl);
            uint2 skq = ((const uint2*)skipp)[(node << 5) + fl];
            float v0 = acc0 + bb.x + bflo_to_f(skq.x);
            float v1 = acc1 + bb.y + bfhi_to_f(skq.x);
            float v2 = acc2 + bb.z + bflo_to_f(skq.y);
            float v3 = acc3 + bb.w + bfhi_to_f(skq.y);
            v0 = v0 > 0.f ? v0 : (__expf(v0) - 1.f);   // ELU
            v1 = v1 > 0.f ? v1 : (__expf(v1) - 1.f);
            v2 = v2 > 0.f ? v2 : (__expf(v2) - 1.f);
            v3 = v3 > 0.f ? v3 : (__expf(v3) - 1.f);
            uint2 o = make_uint2(pk_bf(v0, v1), pk_bf(v2, v3));
            ((uint2*)outp)[(node << 5) + fl] = o;
        }
    } else {
        if (active && lane < OUTC) {
            const float* skip = (const float*)skipp;
            float v = acc0 * 0.25f + bias[lane] + skip[node * OUTC + lane];
            ((float*)outp)[node * OUTC + lane] = v;
        }
    }
}

// ---------------------------------------------------------------------------
extern "C" void kernel_launch(void* const* d_in, const int* in_sizes, int n_in,
                              void* d_out, int out_size, void* d_ws, size_t ws_size,
                              hipStream_t stream) {
    const float* x        = (const float*)d_in[0];
    const int*   ei       = (const int*)d_in[1];
    const float* lin_w0   = (const float*)d_in[2];
    const float* att_src0 = (const float*)d_in[3];
    const float* att_dst0 = (const float*)d_in[4];
    const float* bias0    = (const float*)d_in[5];
    const float* skip_w0  = (const float*)d_in[6];
    const float* skip_b0  = (const float*)d_in[7];
    const float* lin_w1   = (const float*)d_in[8];
    const float* att_src1 = (const float*)d_in[9];
    const float* att_dst1 = (const float*)d_in[10];
    const float* bias1    = (const float*)d_in[11];
    const float* skip_w1  = (const float*)d_in[12];
    const float* skip_b1  = (const float*)d_in[13];
    const float* lin_w2   = (const float*)d_in[14];
    const float* att_src2 = (const float*)d_in[15];
    const float* att_dst2 = (const float*)d_in[16];
    const float* bias2    = (const float*)d_in[17];
    const float* skip_w2  = (const float*)d_in[18];
    const float* skip_b2  = (const float*)d_in[19];
    float* out = (float*)d_out;

    const int N = in_sizes[0] / KD;       // 50000
    const int E = in_sizes[1] / 2;        // 800000
    const int ET_ = E + N;                // with self loops

    char* ws = (char*)d_ws;
    size_t off = 0;
    auto alloc = [&](size_t bytes) -> void* {
        void* p = ws + off;
        off = (off + bytes + 255) & ~(size_t)255;
        return p;
    };
    void*   xh      = alloc((size_t)N * HC * 2 + 256);      // L0/1: bf16 128/row; L2: fp8 192B/row
    __bf16* buf_bf  = (__bf16*)alloc((size_t)N * HC * 2);   // ELU layer output (bf16)
    void*   skipbuf = alloc((size_t)N * HC * 4);            // skip: bf16 L0/1, fp32 L2
    float* a_src    = (float*)alloc((size_t)N * 4 * 4);
    float* a_dst    = (float*)alloc((size_t)N * 4 * 4);
    int* deg        = (int*)alloc((size_t)N * 4);
    int* row_ptr    = (int*)alloc((size_t)N * 4);
    int* fill       = (int*)alloc((size_t)N * 4);
    int* col        = (int*)alloc((size_t)ET_ * 4);
    int* counter    = (int*)alloc(256);
    __bf16* Bt      = (__bf16*)alloc((size_t)3 * 256 * 128 * 2);  // prepped weights

    // ---- weight prep (no deps; overlaps CSR build) ----
    prep_w_kernel<<<384, 256, 0, stream>>>(lin_w0, skip_w0, lin_w1, skip_w1,
                                           lin_w2, skip_w2, Bt);

    // ---- CSR build (dst-sorted adjacency, self-loops included) ----
    hipMemsetAsync(deg, 0, (size_t)N * 4, stream);
    hipMemsetAsync(counter, 0, 4, stream);
    count_kernel<<<(E / 8 + 255) / 256, 256, 0, stream>>>(ei + E, deg, E);
    scan_base_kernel<<<(N + 255) / 256, 256, 0, stream>>>(deg, counter, row_ptr, fill, col, N);
    fill_kernel<<<(E / 8 + 255) / 256, 256, 0, stream>>>(ei, fill, col, E);

    dim3 blk(256);
    int mblocks = (N + 63) / 64;          // BM=64
    int wave_blocks = (N + 3) / 4;        // one wave per node, 4 waves/block
    int att_blocks = (N * 16 + 255) / 256; // 16 threads per node

    // ---- layer 0 (A = fp32 x, converted in staging; skip bf16) ----
    gemm_fused_kernel<float, __bf16, 2, 2, 0><<<mblocks, blk, 0, stream>>>(
        x, Bt, xh, HC, HC, skip_b0, (__bf16*)skipbuf, HC, N);
    att_kernel<<<att_blocks, blk, 0, stream>>>((const __bf16*)xh, att_src0, att_dst0,
                                               a_src, a_dst, N);
    agg_kernel<0><<<wave_blocks, blk, 0, stream>>>(xh, a_src, a_dst, skipbuf, bias0,
                                                   row_ptr, deg, col, buf_bf, N);
    // ---- layer 1 (skip bf16) ----
    gemm_fused_kernel<__bf16, __bf16, 2, 2, 0><<<mblocks, blk, 0, stream>>>(
        buf_bf, Bt + 32768, xh, HC, HC, skip_b1, (__bf16*)skipbuf, HC, N);
    att_kernel<<<att_blocks, blk, 0, stream>>>((const __bf16*)xh, att_src1, att_dst1,
                                               a_src, a_dst, N);
    agg_kernel<0><<<wave_blocks, blk, 0, stream>>>(xh, a_src, a_dst, skipbuf, bias1,
                                                   row_ptr, deg, col, buf_bf, N);
    // ---- layer 2 (xh fp8 e4m3, head-interleaved, 192 B rows; skip fp32) ----
    gemm_fused_kernel<__bf16, float, 3, 1, 1><<<mblocks, blk, 0, stream>>>(
        buf_bf, Bt + 65536, xh, NF2, NF2PB, skip_b2, (float*)skipbuf, OUTC, N);
    att2_kernel<<<wave_blocks, blk, 0, stream>>>((const unsigned char*)xh, att_src2,
                                                 att_dst2, a_src, a_dst, N);
    agg_kernel<1><<<wave_blocks, blk, 0, stream>>>(xh, a_src, a_dst, skipbuf, bias2,
                                                   row_ptr, deg, col, out, N);
}

// Round 2
// 409.766 us; speedup vs baseline: 1.1141x; 1.1141x over previous
//
#include <hip/hip_runtime.h>
#include <math.h>
#include <type_traits>

// Problem constants (fixed by reference)
#define KD 128      // K dim of every GEMM (IN = HC = 128)
#define HC 128      // H*C for layers 0/1
#define NF2 188     // H*OUT for layer 2
#define NF2PB 192   // padded layer-2 row stride in BYTES (fp8: 3 cachelines)
#define OUTC 47

typedef __attribute__((ext_vector_type(8))) __bf16 bf16x8;
typedef __attribute__((ext_vector_type(4))) float f32x4;
typedef __attribute__((ext_vector_type(2))) float f32x2;

#ifdef __has_builtin
#if __has_builtin(__builtin_amdgcn_cvt_pk_f32_fp8)
#define HAVE_CVT_FP8_DEC 1
#endif
#if __has_builtin(__builtin_amdgcn_cvt_pk_fp8_f32)
#define HAVE_CVT_FP8_ENC 1
#endif
#endif

__device__ inline float bfhi_to_f(unsigned int u) {
    union { unsigned int u; float f; } c; c.u = u & 0xFFFF0000u; return c.f;
}
__device__ inline float bflo_to_f(unsigned int u) {
    union { unsigned int u; float f; } c; c.u = u << 16; return c.f;
}
__device__ inline unsigned short f_to_bfu(float f) {
    return __builtin_bit_cast(unsigned short, (__bf16)f);
}
__device__ inline unsigned int pk_bf(float a, float b) {
    return (unsigned int)f_to_bfu(a) | ((unsigned int)f_to_bfu(b) << 16);
}

// acc += x.lo*a.lo + x.hi*a.hi  (bf16 pairs, f32 accumulate) — VOP3P
__device__ inline void dot2bf(float& acc, unsigned int x, unsigned int a) {
    asm("v_dot2_f32_bf16 %0, %1, %2, %0" : "+v"(acc) : "v"(x), "v"(a));
}
// byte-select: result = bytes of (hi:lo) picked by sel
__device__ inline unsigned int permb(unsigned int hi, unsigned int lo, unsigned int sel) {
    return __builtin_amdgcn_perm(hi, lo, sel);
}

// ---- fp8 e4m3 helpers (HW cvt on gfx950; bit-math fallback) ----
#ifndef HAVE_CVT_FP8_DEC
__device__ inline float fp8_to_f32_b(unsigned int b) {
    int e = (b >> 3) & 15, m = b & 7;
    float v = e ? ldexpf((float)(8 + m), e - 10) : ldexpf((float)m, -9);
    return (b & 0x80) ? -v : v;
}
#endif
__device__ inline void fp8x4_dec(unsigned int q, float& a, float& b, float& c, float& d) {
#ifdef HAVE_CVT_FP8_DEC
    f32x2 lo = __builtin_amdgcn_cvt_pk_f32_fp8((int)q, false);
    f32x2 hi = __builtin_amdgcn_cvt_pk_f32_fp8((int)q, true);
    a = lo[0]; b = lo[1]; c = hi[0]; d = hi[1];
#else
    a = fp8_to_f32_b(q & 0xFF); b = fp8_to_f32_b((q >> 8) & 0xFF);
    c = fp8_to_f32_b((q >> 16) & 0xFF); d = fp8_to_f32_b((q >> 24) & 0xFF);
#endif
}
__device__ inline unsigned char f32_to_fp8(float v) {
#ifdef HAVE_CVT_FP8_ENC
    return (unsigned char)(__builtin_amdgcn_cvt_pk_fp8_f32(v, v, 0, false) & 0xFF);
#else
    unsigned u = __builtin_bit_cast(unsigned, v);
    unsigned s = (u >> 24) & 0x80;
    float a = fabsf(v);
    if (a < 0.0009765625f) return (unsigned char)s;
    if (a >= 448.f) return (unsigned char)(s | 0x7E);
    int e; float m = frexpf(a, &e);        // a = m*2^e, m in [0.5,1)
    int E = e - 1 + 7;
    int mi = (int)rintf(m * 16.f);         // in [8,16]
    if (mi == 16) { mi = 8; ++E; if (E >= 16) return (unsigned char)(s | 0x7E); }
    if (E <= 0) {
        int q = (int)rintf(a * 512.f); if (q > 7) q = 7;
        return (unsigned char)(s | q);
    }
    return (unsigned char)(s | (E << 3) | (mi - 8));
#endif
}
// acc += dot(4 fp8 of q, al)
__device__ inline float fp8dot(unsigned int q, float4 al, float acc) {
    float a, b, c, d;
    fp8x4_dec(q, a, b, c, d);
    return acc + al.x * a + al.y * b + al.z * c + al.w * d;
}

// ---------------------------------------------------------------------------
// CSR build: memset(deg,counter) -> count -> scan(+selfloop,+writeback) -> fill
// 2 edges/thread: R1 counters showed 8/thread leaves fill at 11% occupancy,
// 0.2% VALU — pure latency starvation (390 blocks = 1.5/CU). Grid x4.
// ---------------------------------------------------------------------------
__global__ void count_kernel(const int* __restrict__ dst, int* deg, int e) {
    int t = blockIdx.x * blockDim.x + threadIdx.x;
    int base = t * 2;
    if (base + 1 < e) {
        int2 d = *(const int2*)(dst + base);
        atomicAdd(&deg[d.x], 1); atomicAdd(&deg[d.y], 1);
    } else {
        for (int k = base; k < e; ++k) atomicAdd(&deg[dst[k]], 1);
    }
}

__global__ __launch_bounds__(256) void scan_base_kernel(
    int* __restrict__ deg, int* counter,
    int* __restrict__ row_ptr, int* __restrict__ fill, int* __restrict__ col, int n) {
    int i = blockIdx.x * 256 + threadIdx.x;
    int v = (i < n) ? (deg[i] + 1) : 0;
    int lane = threadIdx.x & 63, w = threadIdx.x >> 6;
    int incl = v;
#pragma unroll
    for (int off = 1; off < 64; off <<= 1) {
        int u = __shfl_up(incl, off, 64);
        if (lane >= off) incl += u;
    }
    __shared__ int wsum[4];
    __shared__ int base_sh;
    if (lane == 63) wsum[w] = incl;
    __syncthreads();
    if (threadIdx.x == 0)
        base_sh = atomicAdd(counter, wsum[0] + wsum[1] + wsum[2] + wsum[3]);
    int woff = 0;
    for (int k = 0; k < w; ++k) woff += wsum[k];
    __syncthreads();
    int excl = base_sh + woff + incl - v;
    if (i < n) {
        row_ptr[i] = excl;
        col[excl] = i;        // self-loop at segment head
        fill[i] = excl + 1;   // edges fill after it
        deg[i] = v;           // write back incl. self-loop
    }
}

__global__ void fill_kernel(const int* __restrict__ ei, int* fill, int* col, int e) {
    int t = blockIdx.x * blockDim.x + threadIdx.x;
    int base = t * 2;
    if (base + 1 < e) {
        int2 s = *(const int2*)(ei + base);
        int2 d = *(const int2*)(ei + e + base);
        int p0 = atomicAdd(&fill[d.x], 1);
        int p1 = atomicAdd(&fill[d.y], 1);
        __builtin_nontemporal_store(s.x, &col[p0]);
        __builtin_nontemporal_store(s.y, &col[p1]);
    } else {
        for (int k = base; k < e; ++k) {
            int pos = atomicAdd(&fill[ei[e + k]], 1);
            __builtin_nontemporal_store(ei[k], &col[pos]);
        }
    }
}

// ---------------------------------------------------------------------------
// One-shot weight prep: transpose + convert all 6 weight matrices into padded
// bf16 [n][k] buffers (64-row-aligned tiles, zero rows past true N).
//   Bt layout per layer L (256 rows x 128 k):
//     L0/L1: rows 0..127 = lin_w^T, 128..255 = skip_w^T
//     L2:    rows 0..187 = lin_w2^T, 188..191 = 0, 192..238 = skip_w2^T, rest 0
// ---------------------------------------------------------------------------
__global__ __launch_bounds__(256) void prep_w_kernel(
    const float* __restrict__ lw0, const float* __restrict__ sw0,
    const float* __restrict__ lw1, const float* __restrict__ sw1,
    const float* __restrict__ lw2, const float* __restrict__ sw2,
    __bf16* __restrict__ bt) {
    int idx = blockIdx.x * 256 + threadIdx.x;   // 3 * 256 * 128 = 98304 total
    int buf = idx >> 15;                        // / 32768
    int r = idx & 32767;
    int n = r >> 7, k = r & 127;
    float v = 0.f;
    if (buf == 0) v = (n < 128) ? lw0[k * 128 + n] : sw0[k * 128 + n - 128];
    else if (buf == 1) v = (n < 128) ? lw1[k * 128 + n] : sw1[k * 128 + n - 128];
    else {
        if (n < 188) v = lw2[k * 188 + n];
        else if (n >= 192 && n < 239) v = sw2[k * 47 + n - 192];
    }
    bt[idx] = (__bf16)v;
}

// ---------------------------------------------------------------------------
// Fused bf16 MFMA GEMM: A staged ONCE per block (BM=64); B tile staged to LDS
// per column tile as a STRAIGHT bf16x8 memcpy from the prepped [n][k] buffer
// (no scalar f32 transpose loads — that was R0's staging cost; direct-from-L2
// per MFMA was R1's latency regression).
//   tiles [0, NLIN)        : out0 = A @ lin
//       TR=0: bf16 store, elem stride ldc0
//       TR=1: fp8 e4m3 store, head-interleaved (byte idx = row*ldc0 + oc*4+h)
//   tiles [NLIN, NLIN+NSK) : out1 = A @ skip + bias1 (SKT store)
// ---------------------------------------------------------------------------
template <typename AT, typename SKT, int NLIN, int NSK, int TR>
__global__ __launch_bounds__(256) void gemm_fused_kernel(
    const AT* __restrict__ A, const __bf16* __restrict__ Bt,
    void* __restrict__ out0, int N0, int ldc0,
    const float* __restrict__ bias1, SKT* __restrict__ out1, int N1, int M) {
    __shared__ __bf16 As[64][136];    // [m][k], +8 pad (16B-aligned rows)
    __shared__ __bf16 Bs[64][136];    // [n][k]
    int tid = threadIdx.x;
    int m0 = blockIdx.x * 64;

    // stage A: 64 rows x 128 elems, 16B LDS writes (read once!)
#pragma unroll
    for (int rep = 0; rep < 4; ++rep) {
        int idx = tid + rep * 256;          // 0..1023
        int row = idx >> 4, seg = idx & 15; // 8-elem segment within row
        int gm = m0 + row;
        bf16x8 v = {};
        if (gm < M) {
            if constexpr (std::is_same<AT, float>::value) {
                const float* p = A + gm * KD + seg * 8;
                float4 f0 = *(const float4*)p;
                float4 f1 = *(const float4*)(p + 4);
                v[0] = (__bf16)f0.x; v[1] = (__bf16)f0.y; v[2] = (__bf16)f0.z; v[3] = (__bf16)f0.w;
                v[4] = (__bf16)f1.x; v[5] = (__bf16)f1.y; v[6] = (__bf16)f1.z; v[7] = (__bf16)f1.w;
            } else {
                v = *(const bf16x8*)(A + gm * KD + seg * 8);
            }
        }
        *(bf16x8*)&As[row][seg * 8] = v;
    }
    __syncthreads();

    int w = tid >> 6, lane = tid & 63;
    int lr = lane & 15, quad = lane >> 4;

#pragma unroll
    for (int t = 0; t < NLIN + NSK; ++t) {
        bool second = t >= NLIN;
        int N = second ? N1 : N0;
        int n0 = (second ? (t - NLIN) : t) * 64;
        if (t) __syncthreads();   // all waves done reading previous Bs
        // stage B tile: straight coalesced copy (Bt already [n][k] bf16, padded)
#pragma unroll
        for (int rep = 0; rep < 4; ++rep) {
            int idx = tid + rep * 256;          // 0..1023
            int row = idx >> 4, seg = idx & 15;
            *(bf16x8*)&Bs[row][seg * 8] =
                *(const bf16x8*)(Bt + ((t * 64 + row) << 7) + seg * 8);
        }
        __syncthreads();

        f32x4 acc[4] = {};
#pragma unroll
        for (int kc = 0; kc < 128; kc += 32) {
            bf16x8 a0 = *(const bf16x8*)&As[w * 16 + lr][kc + quad * 8];
            bf16x8 b0 = *(const bf16x8*)&Bs[lr][kc + quad * 8];
            bf16x8 b1 = *(const bf16x8*)&Bs[16 + lr][kc + quad * 8];
            bf16x8 b2 = *(const bf16x8*)&Bs[32 + lr][kc + quad * 8];
            bf16x8 b3 = *(const bf16x8*)&Bs[48 + lr][kc + quad * 8];
            acc[0] = __builtin_amdgcn_mfma_f32_16x16x32_bf16(a0, b0, acc[0], 0, 0, 0);
            acc[1] = __builtin_amdgcn_mfma_f32_16x16x32_bf16(a0, b1, acc[1], 0, 0, 0);
            acc[2] = __builtin_amdgcn_mfma_f32_16x16x32_bf16(a0, b2, acc[2], 0, 0, 0);
            acc[3] = __builtin_amdgcn_mfma_f32_16x16x32_bf16(a0, b3, acc[3], 0, 0, 0);
        }
        // epilogue: C/D layout col=lane&15, row=quad*4+reg
#pragma unroll
        for (int c = 0; c < 4; ++c) {
#pragma unroll
            for (int reg = 0; reg < 4; ++reg) {
                int row = m0 + w * 16 + quad * 4 + reg;
                int colg = n0 + c * 16 + lr;
                if (row < M && colg < N) {
                    float v = acc[c][reg];
                    if (second) {
                        v += bias1[colg];
                        out1[row * N + colg] = (SKT)v;
                    } else if (TR) {   // fp8, head-interleaved: byte = oc*4 + h
                        int h = (colg * 1395) >> 16;   // colg / 47 for colg<188
                        ((unsigned char*)out0)[row * ldc0 + (colg - 47 * h) * 4 + h] =
                            f32_to_fp8(v);
                    } else {
                        ((__bf16*)out0)[row * ldc0 + colg] = (__bf16)v;
                    }
                }
            }
        }
    }
}

// ---------------------------------------------------------------------------
// att for layers 0/1: 16 lanes per node (4 nodes/wave). Lane owns 8 feats =
// one head-quarter (head = l16>>2) -> single accumulator; 2-round reduce.
// ---------------------------------------------------------------------------
__global__ __launch_bounds__(256) void att_kernel(
    const __bf16* __restrict__ xh, const float* __restrict__ att_s,
    const float* __restrict__ att_d, float* __restrict__ a_src,
    float* __restrict__ a_dst, int n) {
    int tid = blockIdx.x * 256 + threadIdx.x;
    int node = tid >> 4;
    int l16 = threadIdx.x & 15;
    if (node >= n) return;
    uint4 q = ((const uint4*)xh)[node * 16 + l16];   // 8 bf16 feats
    int f0 = l16 * 8;
    float4 as0 = *(const float4*)(att_s + f0);
    float4 as1 = *(const float4*)(att_s + f0 + 4);
    float4 ad0 = *(const float4*)(att_d + f0);
    float4 ad1 = *(const float4*)(att_d + f0 + 4);
    float x0 = bflo_to_f(q.x), x1 = bfhi_to_f(q.x);
    float x2 = bflo_to_f(q.y), x3 = bfhi_to_f(q.y);
    float x4 = bflo_to_f(q.z), x5 = bfhi_to_f(q.z);
    float x6 = bflo_to_f(q.w), x7 = bfhi_to_f(q.w);
    float hs = x0 * as0.x + x1 * as0.y + x2 * as0.z + x3 * as0.w
             + x4 * as1.x + x5 * as1.y + x6 * as1.z + x7 * as1.w;
    float hd = x0 * ad0.x + x1 * ad0.y + x2 * ad0.z + x3 * ad0.w
             + x4 * ad1.x + x5 * ad1.y + x6 * ad1.z + x7 * ad1.w;
    hs += __shfl_xor(hs, 1, 64); hs += __shfl_xor(hs, 2, 64);
    hd += __shfl_xor(hd, 1, 64); hd += __shfl_xor(hd, 2, 64);
    if ((l16 & 3) == 0) {
        int h = l16 >> 2;
        a_src[node * 4 + h] = hs;
        a_dst[node * 4 + h] = hd;
    }
}

// ---------------------------------------------------------------------------
// att for layer 2 (fp8 head-interleaved xh, 192 B rows): lane<47 loads one
// uint = 4 heads of channel c=lane; per-head partials; 6-round butterfly.
// ---------------------------------------------------------------------------
__global__ __launch_bounds__(256) void att2_kernel(
    const unsigned char* __restrict__ xh8, const float* __restrict__ att_s,
    const float* __restrict__ att_d, float* __restrict__ a_src,
    float* __restrict__ a_dst, int n) {
    int node = (blockIdx.x * 256 + threadIdx.x) >> 6;
    int lane = threadIdx.x & 63;
    if (node >= n) return;
    float ps0 = 0.f, ps1 = 0.f, ps2 = 0.f, ps3 = 0.f;
    float pd0 = 0.f, pd1 = 0.f, pd2 = 0.f, pd3 = 0.f;
    if (lane < 47) {
        unsigned int q = ((const unsigned int*)(xh8 + node * NF2PB))[lane];
        float x0, x1, x2, x3;
        fp8x4_dec(q, x0, x1, x2, x3);
        ps0 = x0 * att_s[lane];       ps1 = x1 * att_s[47 + lane];
        ps2 = x2 * att_s[94 + lane];  ps3 = x3 * att_s[141 + lane];
        pd0 = x0 * att_d[lane];       pd1 = x1 * att_d[47 + lane];
        pd2 = x2 * att_d[94 + lane];  pd3 = x3 * att_d[141 + lane];
    }
#pragma unroll
    for (int off = 1; off <= 32; off <<= 1) {
        ps0 += __shfl_xor(ps0, off, 64); ps1 += __shfl_xor(ps1, off, 64);
        ps2 += __shfl_xor(ps2, off, 64); ps3 += __shfl_xor(ps3, off, 64);
        pd0 += __shfl_xor(pd0, off, 64); pd1 += __shfl_xor(pd1, off, 64);
        pd2 += __shfl_xor(pd2, off, 64); pd3 += __shfl_xor(pd3, off, 64);
    }
    if (lane < 4) {
        float vs = (lane == 0) ? ps0 : (lane == 1) ? ps1 : (lane == 2) ? ps2 : ps3;
        float vd = (lane == 0) ? pd0 : (lane == 1) ? pd1 : (lane == 2) ? pd2 : pd3;
        a_src[node * 4 + lane] = vs;
        a_dst[node * 4 + lane] = vd;
    }
}

// ---------------------------------------------------------------------------
// Aggregation: one wave per destination node. 32-bit indexing.
// No-max softmax (logits O(1-10); fp32 exp safe) — verified R10.
// MODE 0 (bf16 xh, 128 feats): half-wave per EDGE PAIR; lane fl owns feats
//   4fl..4fl+3. v_perm builds same-feat bf16 pairs from the two edges,
//   v_dot2_f32_bf16 with packed bf16 alpha-pair does 2 products/instr.
//   skip bf16, out bf16+ELU.
// MODE 1 (fp8 xh, 192 B rows, head-interleaved): lane c<47 loads uint =
//   4 heads of channel c; fp32 alphas; fp8dot. skip fp32, out fp32.
// ---------------------------------------------------------------------------
template <int MODE>
__global__ __launch_bounds__(256) void agg_kernel(
    const void* __restrict__ xhp, const float* __restrict__ a_src,
    const float* __restrict__ a_dst, const void* __restrict__ skipp,
    const float* __restrict__ bias, const int* __restrict__ row_ptr,
    const int* __restrict__ deg, const int* __restrict__ col,
    void* __restrict__ outp, int n) {
    __shared__ float s_af[4][64][4];      // MODE 1: f32 alphas
    __shared__ unsigned s_ap[4][32][4];   // MODE 0: packed bf16 alpha pairs [pair][head]
    __shared__ int s_j[4][64];
    int w = threadIdx.x >> 6;
    int lane = threadIdx.x & 63;
    int node = (blockIdx.x << 2) + w;
    bool active = node < n;
    int node_c = active ? node : 0;
    int start = row_ptr[node_c];
    int end = start + (active ? deg[node_c] : 0);
    float4 ad4 = *(const float4*)(a_dst + 4 * node_c);
    float adh[4] = {ad4.x, ad4.y, ad4.z, ad4.w};

    // ---- pass A: sum of exp per head (+ chunk-0 exp capture) ----
    int e0 = start + lane;
    bool ok0 = e0 < end;
    int jcap = ok0 ? col[e0] : 0;
    float evc[4];   // exp(leaky(e)) for this lane's chunk-0 edge
    {
        float4 as4 = *(const float4*)(a_src + 4 * jcap);
        float v0 = as4.x + adh[0]; v0 = v0 > 0.f ? v0 : 0.2f * v0;
        float v1 = as4.y + adh[1]; v1 = v1 > 0.f ? v1 : 0.2f * v1;
        float v2 = as4.z + adh[2]; v2 = v2 > 0.f ? v2 : 0.2f * v2;
        float v3 = as4.w + adh[3]; v3 = v3 > 0.f ? v3 : 0.2f * v3;
        evc[0] = ok0 ? __expf(v0) : 0.f;
        evc[1] = ok0 ? __expf(v1) : 0.f;
        evc[2] = ok0 ? __expf(v2) : 0.f;
        evc[3] = ok0 ? __expf(v3) : 0.f;
    }
    float s[4] = {evc[0], evc[1], evc[2], evc[3]};
    for (int e = e0 + 64; e < end; e += 64) {
        int j = col[e];
        float4 as4 = *(const float4*)(a_src + 4 * j);
        float ev[4] = {as4.x + adh[0], as4.y + adh[1], as4.z + adh[2], as4.w + adh[3]};
#pragma unroll
        for (int h = 0; h < 4; ++h) {
            float v = ev[h] > 0.f ? ev[h] : 0.2f * ev[h];
            s[h] += __expf(v);
        }
    }
#pragma unroll
    for (int off = 32; off >= 1; off >>= 1)
#pragma unroll
        for (int h = 0; h < 4; ++h) s[h] += __shfl_xor(s[h], off, 64);
    float inv[4];
#pragma unroll
    for (int h = 0; h < 4; ++h) inv[h] = 1.f / (s[h] + 1e-16f);

    // ---- pass B bookkeeping ----
    int half = lane >> 5, fl = lane & 31, myh2 = fl >> 3;
    bool lv = lane < 47;  // MODE 1 active lanes (channel c = lane)
    float acc0 = 0.f, acc1 = 0.f, acc2 = 0.f, acc3 = 0.f;
    const uint2* xb2 = (const uint2*)xhp;           // MODE 0
    const unsigned int* x8 = (const unsigned int*)xhp;  // MODE 1 (48 uints/row)

    auto run_chunk = [&](int cnt) {
        if constexpr (MODE == 0) {
            // edge-pair loop: half h walks pairs h, h+2, h+4, ...
            int npair = (cnt + 1) >> 1;
            int p = half;
            for (; p + 2 < npair; p += 4) {
                int2 j0 = *(const int2*)&s_j[w][2 * p];
                int2 j1 = *(const int2*)&s_j[w][2 * p + 4];
                unsigned ap0 = s_ap[w][p][myh2];
                unsigned ap1 = s_ap[w][p + 2][myh2];
                uint2 qa0 = xb2[(j0.x << 5) + fl];
                uint2 qb0 = xb2[(j0.y << 5) + fl];
                uint2 qa1 = xb2[(j1.x << 5) + fl];
                uint2 qb1 = xb2[(j1.y << 5) + fl];
                dot2bf(acc0, permb(qb0.x, qa0.x, 0x05040100u), ap0);
                dot2bf(acc1, permb(qb0.x, qa0.x, 0x07060302u), ap0);
                dot2bf(acc2, permb(qb0.y, qa0.y, 0x05040100u), ap0);
                dot2bf(acc3, permb(qb0.y, qa0.y, 0x07060302u), ap0);
                dot2bf(acc0, permb(qb1.x, qa1.x, 0x05040100u), ap1);
                dot2bf(acc1, permb(qb1.x, qa1.x, 0x07060302u), ap1);
                dot2bf(acc2, permb(qb1.y, qa1.y, 0x05040100u), ap1);
                dot2bf(acc3, permb(qb1.y, qa1.y, 0x07060302u), ap1);
            }
            for (; p < npair; p += 2) {
                int2 j0 = *(const int2*)&s_j[w][2 * p];
                unsigned ap0 = s_ap[w][p][myh2];
                uint2 qa0 = xb2[(j0.x << 5) + fl];
                uint2 qb0 = xb2[(j0.y << 5) + fl];
                dot2bf(acc0, permb(qb0.x, qa0.x, 0x05040100u), ap0);
                dot2bf(acc1, permb(qb0.x, qa0.x, 0x07060302u), ap0);
                dot2bf(acc2, permb(qb0.y, qa0.y, 0x05040100u), ap0);
                dot2bf(acc3, permb(qb0.y, qa0.y, 0x07060302u), ap0);
            }
        } else {
            int t = 0;
            for (; t + 7 < cnt; t += 8) {
                unsigned int q0 = lv ? x8[s_j[w][t] * 48 + lane] : 0u;
                unsigned int q1 = lv ? x8[s_j[w][t + 1] * 48 + lane] : 0u;
                unsigned int q2 = lv ? x8[s_j[w][t + 2] * 48 + lane] : 0u;
                unsigned int q3 = lv ? x8[s_j[w][t + 3] * 48 + lane] : 0u;
                unsigned int q4 = lv ? x8[s_j[w][t + 4] * 48 + lane] : 0u;
                unsigned int q5 = lv ? x8[s_j[w][t + 5] * 48 + lane] : 0u;
                unsigned int q6 = lv ? x8[s_j[w][t + 6] * 48 + lane] : 0u;
                unsigned int q7 = lv ? x8[s_j[w][t + 7] * 48 + lane] : 0u;
                acc0 = fp8dot(q0, *(const float4*)&s_af[w][t][0], acc0);
                acc0 = fp8dot(q1, *(const float4*)&s_af[w][t + 1][0], acc0);
                acc0 = fp8dot(q2, *(const float4*)&s_af[w][t + 2][0], acc0);
                acc0 = fp8dot(q3, *(const float4*)&s_af[w][t + 3][0], acc0);
                acc0 = fp8dot(q4, *(const float4*)&s_af[w][t + 4][0], acc0);
                acc0 = fp8dot(q5, *(const float4*)&s_af[w][t + 5][0], acc0);
                acc0 = fp8dot(q6, *(const float4*)&s_af[w][t + 6][0], acc0);
                acc0 = fp8dot(q7, *(const float4*)&s_af[w][t + 7][0], acc0);
            }
            for (; t + 3 < cnt; t += 4) {
                unsigned int q0 = lv ? x8[s_j[w][t] * 48 + lane] : 0u;
                unsigned int q1 = lv ? x8[s_j[w][t + 1] * 48 + lane] : 0u;
                unsigned int q2 = lv ? x8[s_j[w][t + 2] * 48 + lane] : 0u;
                unsigned int q3 = lv ? x8[s_j[w][t + 3] * 48 + lane] : 0u;
                acc0 = fp8dot(q0, *(const float4*)&s_af[w][t][0], acc0);
                acc0 = fp8dot(q1, *(const float4*)&s_af[w][t + 1][0], acc0);
                acc0 = fp8dot(q2, *(const float4*)&s_af[w][t + 2][0], acc0);
                acc0 = fp8dot(q3, *(const float4*)&s_af[w][t + 3][0], acc0);
            }
            for (; t < cnt; ++t) {
                unsigned int q = lv ? x8[s_j[w][t] * 48 + lane] : 0u;
                acc0 = fp8dot(q, *(const float4*)&s_af[w][t][0], acc0);
            }
        }
    };

    // chunk 0: reuse captured exp values, no col/a_src reload
    {
        float al[4];
#pragma unroll
        for (int h = 0; h < 4; ++h) al[h] = evc[h] * inv[h];
        s_j[w][lane] = jcap;
        if constexpr (MODE == 0) {
            float o0 = __shfl_xor(al[0], 1, 64);
            float o1 = __shfl_xor(al[1], 1, 64);
            float o2 = __shfl_xor(al[2], 1, 64);
            float o3 = __shfl_xor(al[3], 1, 64);
            if (!(lane & 1)) {
                uint4 pk = make_uint4(pk_bf(al[0], o0), pk_bf(al[1], o1),
                                      pk_bf(al[2], o2), pk_bf(al[3], o3));
                *(uint4*)&s_ap[w][lane >> 1][0] = pk;
            }
        } else {
            *(float4*)&s_af[w][lane][0] = make_float4(al[0], al[1], al[2], al[3]);
        }
        int cnt = end - start; if (cnt > 64) cnt = 64;
        run_chunk(cnt);
    }
    // remaining chunks (deg > 64: rare)
    for (int base = start + 64; base < end; base += 64) {
        int e = base + lane;
        bool ok = e < end;
        int jv = ok ? col[e] : 0;
        float4 as4 = *(const float4*)(a_src + 4 * jv);
        float asv[4] = {as4.x, as4.y, as4.z, as4.w};
        float al[4];
#pragma unroll
        for (int h = 0; h < 4; ++h) {
            float ev = asv[h] + adh[h];
            ev = ev > 0.f ? ev : 0.2f * ev;
            al[h] = ok ? __expf(ev) * inv[h] : 0.f;
        }
        s_j[w][lane] = jv;
        if constexpr (MODE == 0) {
            float o0 = __shfl_xor(al[0], 1, 64);
            float o1 = __shfl_xor(al[1], 1, 64);
            float o2 = __shfl_xor(al[2], 1, 64);
            float o3 = __shfl_xor(al[3], 1, 64);
            if (!(lane & 1)) {
                uint4 pk = make_uint4(pk_bf(al[0], o0), pk_bf(al[1], o1),
                                      pk_bf(al[2], o2), pk_bf(al[3], o3));
                *(uint4*)&s_ap[w][lane >> 1][0] = pk;
            }
        } else {
            *(float4*)&s_af[w][lane][0] = make_float4(al[0], al[1], al[2], al[3]);
        }
        int cnt = end - base; if (cnt > 64) cnt = 64;
        run_chunk(cnt);
    }

    if constexpr (MODE == 0) {
        // combine half-waves (each half accumulated its own pair subset)
        acc0 += __shfl_xor(acc0, 32, 64);
        acc1 += __shfl_xor(acc1, 32, 64);
        acc2 += __shfl_xor(acc2, 32, 64);
        acc3 += __shfl_xor(acc3, 32, 64);
        if (active && half == 0) {
            float4 bb = *(const float4*)(bias + 4 * fl);
            uint2 skq = ((const uint2*)skipp)[(node << 5) + fl];
            float v0 = acc0 + bb.x + bflo_to_f(skq.x);
            float v1 = acc1 + bb.y + bfhi_to_f(skq.x);
            float v2 = acc2 + bb.z + bflo_to_f(skq.y);
            float v3 = acc3 + bb.w + bfhi_to_f(skq.y);
            v0 = v0 > 0.f ? v0 : (__expf(v0) - 1.f);   // ELU
            v1 = v1 > 0.f ? v1 : (__expf(v1) - 1.f);
            v2 = v2 > 0.f ? v2 : (__expf(v2) - 1.f);
            v3 = v3 > 0.f ? v3 : (__expf(v3) - 1.f);
            uint2 o = make_uint2(pk_bf(v0, v1), pk_bf(v2, v3));
            ((uint2*)outp)[(node << 5) + fl] = o;
        }
    } else {
        if (active && lane < OUTC) {
            const float* skip = (const float*)skipp;
            float v = acc0 * 0.25f + bias[lane] + skip[node * OUTC + lane];
            ((float*)outp)[node * OUTC + lane] = v;
        }
    }
}

// ---------------------------------------------------------------------------
extern "C" void kernel_launch(void* const* d_in, const int* in_sizes, int n_in,
                              void* d_out, int out_size, void* d_ws, size_t ws_size,
                              hipStream_t stream) {
    const float* x        = (const float*)d_in[0];
    const int*   ei       = (const int*)d_in[1];
    const float* lin_w0   = (const float*)d_in[2];
    const float* att_src0 = (const float*)d_in[3];
    const float* att_dst0 = (const float*)d_in[4];
    const float* bias0    = (const float*)d_in[5];
    const float* skip_w0  = (const float*)d_in[6];
    const float* skip_b0  = (const float*)d_in[7];
    const float* lin_w1   = (const float*)d_in[8];
    const float* att_src1 = (const float*)d_in[9];
    const float* att_dst1 = (const float*)d_in[10];
    const float* bias1    = (const float*)d_in[11];
    const float* skip_w1  = (const float*)d_in[12];
    const float* skip_b1  = (const float*)d_in[13];
    const float* lin_w2   = (const float*)d_in[14];
    const float* att_src2 = (const float*)d_in[15];
    const float* att_dst2 = (const float*)d_in[16];
    const float* bias2    = (const float*)d_in[17];
    const float* skip_w2  = (const float*)d_in[18];
    const float* skip_b2  = (const float*)d_in[19];
    float* out = (float*)d_out;

    const int N = in_sizes[0] / KD;       // 50000
    const int E = in_sizes[1] / 2;        // 800000
    const int ET_ = E + N;                // with self loops

    char* ws = (char*)d_ws;
    size_t off = 0;
    auto alloc = [&](size_t bytes) -> void* {
        void* p = ws + off;
        off = (off + bytes + 255) & ~(size_t)255;
        return p;
    };
    void*   xh      = alloc((size_t)N * HC * 2 + 256);      // L0/1: bf16 128/row; L2: fp8 192B/row
    __bf16* buf_bf  = (__bf16*)alloc((size_t)N * HC * 2);   // ELU layer output (bf16)
    void*   skipbuf = alloc((size_t)N * HC * 4);            // skip: bf16 L0/1, fp32 L2
    float* a_src    = (float*)alloc((size_t)N * 4 * 4);
    float* a_dst    = (float*)alloc((size_t)N * 4 * 4);
    int* deg        = (int*)alloc((size_t)N * 4);
    int* row_ptr    = (int*)alloc((size_t)N * 4);
    int* fill       = (int*)alloc((size_t)N * 4);
    int* col        = (int*)alloc((size_t)ET_ * 4);
    int* counter    = (int*)alloc(256);
    __bf16* Bt      = (__bf16*)alloc((size_t)3 * 256 * 128 * 2);  // prepped weights

    // ---- weight prep (no deps; overlaps CSR build) ----
    prep_w_kernel<<<384, 256, 0, stream>>>(lin_w0, skip_w0, lin_w1, skip_w1,
                                           lin_w2, skip_w2, Bt);

    // ---- CSR build (dst-sorted adjacency, self-loops included) ----
    hipMemsetAsync(deg, 0, (size_t)N * 4, stream);
    hipMemsetAsync(counter, 0, 4, stream);
    count_kernel<<<(E / 2 + 255) / 256, 256, 0, stream>>>(ei + E, deg, E);
    scan_base_kernel<<<(N + 255) / 256, 256, 0, stream>>>(deg, counter, row_ptr, fill, col, N);
    fill_kernel<<<(E / 2 + 255) / 256, 256, 0, stream>>>(ei, fill, col, E);

    dim3 blk(256);
    int mblocks = (N + 63) / 64;          // BM=64
    int wave_blocks = (N + 3) / 4;        // one wave per node, 4 waves/block
    int att_blocks = (N * 16 + 255) / 256; // 16 threads per node

    // ---- layer 0 (A = fp32 x, converted in staging; skip bf16) ----
    gemm_fused_kernel<float, __bf16, 2, 2, 0><<<mblocks, blk, 0, stream>>>(
        x, Bt, xh, HC, HC, skip_b0, (__bf16*)skipbuf, HC, N);
    att_kernel<<<att_blocks, blk, 0, stream>>>((const __bf16*)xh, att_src0, att_dst0,
                                               a_src, a_dst, N);
    agg_kernel<0><<<wave_blocks, blk, 0, stream>>>(xh, a_src, a_dst, skipbuf, bias0,
                                                   row_ptr, deg, col, buf_bf, N);
    // ---- layer 1 (skip bf16) ----
    gemm_fused_kernel<__bf16, __bf16, 2, 2, 0><<<mblocks, blk, 0, stream>>>(
        buf_bf, Bt + 32768, xh, HC, HC, skip_b1, (__bf16*)skipbuf, HC, N);
    att_kernel<<<att_blocks, blk, 0, stream>>>((const __bf16*)xh, att_src1, att_dst1,
                                               a_src, a_dst, N);
    agg_kernel<0><<<wave_blocks, blk, 0, stream>>>(xh, a_src, a_dst, skipbuf, bias1,
                                                   row_ptr, deg, col, buf_bf, N);
    // ---- layer 2 (xh fp8 e4m3, head-interleaved, 192 B rows; skip fp32) ----
    gemm_fused_kernel<__bf16, float, 3, 1, 1><<<mblocks, blk, 0, stream>>>(
        buf_bf, Bt + 65536, xh, NF2, NF2PB, skip_b2, (float*)skipbuf, OUTC, N);
    att2_kernel<<<wave_blocks, blk, 0, stream>>>((const unsigned char*)xh, att_src2,
                                                 att_dst2, a_src, a_dst, N);
    agg_kernel<1><<<wave_blocks, blk, 0, stream>>>(xh, a_src, a_dst, skipbuf, bias2,
                                                   row_ptr, deg, col, out, N);
}

// Round 3
// 392.470 us; speedup vs baseline: 1.1632x; 1.0441x over previous
//
#include <hip/hip_runtime.h>
#include <math.h>
#include <type_traits>

// Problem constants (fixed by reference)
#define KD 128      // K dim of every GEMM (IN = HC = 128)
#define HC 128      // H*C for layers 0/1
#define NF2 188     // H*OUT for layer 2
#define NF2PB 192   // padded layer-2 row stride in BYTES (fp8: 3 cachelines)
#define OUTC 47

typedef __attribute__((ext_vector_type(8))) __bf16 bf16x8;
typedef __attribute__((ext_vector_type(4))) float f32x4;
typedef __attribute__((ext_vector_type(2))) float f32x2;

#ifdef __has_builtin
#if __has_builtin(__builtin_amdgcn_cvt_pk_f32_fp8)
#define HAVE_CVT_FP8_DEC 1
#endif
#if __has_builtin(__builtin_amdgcn_cvt_pk_fp8_f32)
#define HAVE_CVT_FP8_ENC 1
#endif
#endif

__device__ inline float bfhi_to_f(unsigned int u) {
    union { unsigned int u; float f; } c; c.u = u & 0xFFFF0000u; return c.f;
}
__device__ inline float bflo_to_f(unsigned int u) {
    union { unsigned int u; float f; } c; c.u = u << 16; return c.f;
}
__device__ inline unsigned short f_to_bfu(float f) {
    return __builtin_bit_cast(unsigned short, (__bf16)f);
}
__device__ inline unsigned int pk_bf(float a, float b) {
    return (unsigned int)f_to_bfu(a) | ((unsigned int)f_to_bfu(b) << 16);
}

// acc += x.lo*a.lo + x.hi*a.hi  (bf16 pairs, f32 accumulate) — VOP3P
__device__ inline void dot2bf(float& acc, unsigned int x, unsigned int a) {
    asm("v_dot2_f32_bf16 %0, %1, %2, %0" : "+v"(acc) : "v"(x), "v"(a));
}
// byte-select: result = bytes of (hi:lo) picked by sel
__device__ inline unsigned int permb(unsigned int hi, unsigned int lo, unsigned int sel) {
    return __builtin_amdgcn_perm(hi, lo, sel);
}

// ---- fp8 e4m3 helpers (HW cvt on gfx950; bit-math fallback) ----
#ifndef HAVE_CVT_FP8_DEC
__device__ inline float fp8_to_f32_b(unsigned int b) {
    int e = (b >> 3) & 15, m = b & 7;
    float v = e ? ldexpf((float)(8 + m), e - 10) : ldexpf((float)m, -9);
    return (b & 0x80) ? -v : v;
}
#endif
__device__ inline void fp8x4_dec(unsigned int q, float& a, float& b, float& c, float& d) {
#ifdef HAVE_CVT_FP8_DEC
    f32x2 lo = __builtin_amdgcn_cvt_pk_f32_fp8((int)q, false);
    f32x2 hi = __builtin_amdgcn_cvt_pk_f32_fp8((int)q, true);
    a = lo[0]; b = lo[1]; c = hi[0]; d = hi[1];
#else
    a = fp8_to_f32_b(q & 0xFF); b = fp8_to_f32_b((q >> 8) & 0xFF);
    c = fp8_to_f32_b((q >> 16) & 0xFF); d = fp8_to_f32_b((q >> 24) & 0xFF);
#endif
}
__device__ inline unsigned char f32_to_fp8(float v) {
#ifdef HAVE_CVT_FP8_ENC
    return (unsigned char)(__builtin_amdgcn_cvt_pk_fp8_f32(v, v, 0, false) & 0xFF);
#else
    unsigned u = __builtin_bit_cast(unsigned, v);
    unsigned s = (u >> 24) & 0x80;
    float a = fabsf(v);
    if (a < 0.0009765625f) return (unsigned char)s;
    if (a >= 448.f) return (unsigned char)(s | 0x7E);
    int e; float m = frexpf(a, &e);        // a = m*2^e, m in [0.5,1)
    int E = e - 1 + 7;
    int mi = (int)rintf(m * 16.f);         // in [8,16]
    if (mi == 16) { mi = 8; ++E; if (E >= 16) return (unsigned char)(s | 0x7E); }
    if (E <= 0) {
        int q = (int)rintf(a * 512.f); if (q > 7) q = 7;
        return (unsigned char)(s | q);
    }
    return (unsigned char)(s | (E << 3) | (mi - 8));
#endif
}
// acc += dot(4 fp8 of q, al)
__device__ inline float fp8dot(unsigned int q, float4 al, float acc) {
    float a, b, c, d;
    fp8x4_dec(q, a, b, c, d);
    return acc + al.x * a + al.y * b + al.z * c + al.w * d;
}

// ---------------------------------------------------------------------------
// CSR build: memset(deg,counter) -> count -> scan(+selfloop,+writeback) -> fill
//
// R2 post-mortem: fill's WRITE_SIZE was 53-59 MB for a 3.4 MB col array —
// 17x write amplification from cross-XCD false sharing (same col cacheline
// dirtied in 8 non-coherent L2s, each writing partial lines through HBM).
// Fix: 8-way dst-range partitioning. Block b scans edge-chunk (b>>3) and
// processes only dsts in range r = b&7. Static (chunk,range) assignment is
// correct under ANY block->XCD mapping; with the usual round-robin placement
// all writers of a col line sit on one XCD -> full-line writeback, once.
// ---------------------------------------------------------------------------
#define NPART 8
#define EPB 2048   // edges per chunk (256 thr x 8)

__global__ __launch_bounds__(256) void count_kernel(
    const int* __restrict__ dst, int* deg, int e, int rngsz) {
    int r = blockIdx.x & (NPART - 1);
    int chunk = blockIdx.x / NPART;
    int base = chunk * EPB + threadIdx.x * 8;
    int lo = r * rngsz, hi = lo + rngsz;
    if (base >= e) return;
    if (base + 7 < e) {
        int4 d0 = *(const int4*)(dst + base);
        int4 d1 = *(const int4*)(dst + base + 4);
        int dd[8] = {d0.x, d0.y, d0.z, d0.w, d1.x, d1.y, d1.z, d1.w};
#pragma unroll
        for (int k = 0; k < 8; ++k)
            if (dd[k] >= lo && dd[k] < hi) atomicAdd(&deg[dd[k]], 1);
    } else {
        for (int k = base; k < e; ++k) {
            int d = dst[k];
            if (d >= lo && d < hi) atomicAdd(&deg[d], 1);
        }
    }
}

__global__ __launch_bounds__(256) void scan_base_kernel(
    int* __restrict__ deg, int* counter,
    int* __restrict__ row_ptr, int* __restrict__ fill, int* __restrict__ col, int n) {
    int i = blockIdx.x * 256 + threadIdx.x;
    int v = (i < n) ? (deg[i] + 1) : 0;
    int lane = threadIdx.x & 63, w = threadIdx.x >> 6;
    int incl = v;
#pragma unroll
    for (int off = 1; off < 64; off <<= 1) {
        int u = __shfl_up(incl, off, 64);
        if (lane >= off) incl += u;
    }
    __shared__ int wsum[4];
    __shared__ int base_sh;
    if (lane == 63) wsum[w] = incl;
    __syncthreads();
    if (threadIdx.x == 0)
        base_sh = atomicAdd(counter, wsum[0] + wsum[1] + wsum[2] + wsum[3]);
    int woff = 0;
    for (int k = 0; k < w; ++k) woff += wsum[k];
    __syncthreads();
    int excl = base_sh + woff + incl - v;
    if (i < n) {
        row_ptr[i] = excl;
        col[excl] = i;        // self-loop at segment head
        fill[i] = excl + 1;   // edges fill after it
        deg[i] = v;           // write back incl. self-loop
    }
}

__global__ __launch_bounds__(256) void fill_kernel(
    const int* __restrict__ ei, int* fill, int* col, int e, int rngsz) {
    int r = blockIdx.x & (NPART - 1);
    int chunk = blockIdx.x / NPART;
    int base = chunk * EPB + threadIdx.x * 8;
    int lo = r * rngsz, hi = lo + rngsz;
    if (base >= e) return;
    const int* dstp = ei + e;
    if (base + 7 < e) {
        int4 d0 = *(const int4*)(dstp + base);
        int4 d1 = *(const int4*)(dstp + base + 4);
        int dd[8] = {d0.x, d0.y, d0.z, d0.w, d1.x, d1.y, d1.z, d1.w};
#pragma unroll
        for (int k = 0; k < 8; ++k) {
            if (dd[k] >= lo && dd[k] < hi) {
                int pos = atomicAdd(&fill[dd[k]], 1);
                col[pos] = ei[base + k];
            }
        }
    } else {
        for (int k = base; k < e; ++k) {
            int d = dstp[k];
            if (d >= lo && d < hi) {
                int pos = atomicAdd(&fill[d], 1);
                col[pos] = ei[k];
            }
        }
    }
}

// ---------------------------------------------------------------------------
// One-shot weight prep: transpose + convert all 6 weight matrices into padded
// bf16 [n][k] buffers (64-row-aligned tiles, zero rows past true N).
//   Bt layout per layer L (256 rows x 128 k):
//     L0/L1: rows 0..127 = lin_w^T, 128..255 = skip_w^T
//     L2:    rows 0..187 = lin_w2^T, 188..191 = 0, 192..238 = skip_w2^T, rest 0
// ---------------------------------------------------------------------------
__global__ __launch_bounds__(256) void prep_w_kernel(
    const float* __restrict__ lw0, const float* __restrict__ sw0,
    const float* __restrict__ lw1, const float* __restrict__ sw1,
    const float* __restrict__ lw2, const float* __restrict__ sw2,
    __bf16* __restrict__ bt) {
    int idx = blockIdx.x * 256 + threadIdx.x;   // 3 * 256 * 128 = 98304 total
    int buf = idx >> 15;                        // / 32768
    int r = idx & 32767;
    int n = r >> 7, k = r & 127;
    float v = 0.f;
    if (buf == 0) v = (n < 128) ? lw0[k * 128 + n] : sw0[k * 128 + n - 128];
    else if (buf == 1) v = (n < 128) ? lw1[k * 128 + n] : sw1[k * 128 + n - 128];
    else {
        if (n < 188) v = lw2[k * 188 + n];
        else if (n >= 192 && n < 239) v = sw2[k * 47 + n - 192];
    }
    bt[idx] = (__bf16)v;
}

// ---------------------------------------------------------------------------
// Fused bf16 MFMA GEMM: A staged ONCE per block (BM=64); B tile staged to LDS
// per column tile as a STRAIGHT bf16x8 memcpy from the prepped [n][k] buffer
// (no scalar f32 transpose loads — that was R0's staging cost; direct-from-L2
// per MFMA was R1's latency regression).
//   tiles [0, NLIN)        : out0 = A @ lin
//       TR=0: bf16 store, elem stride ldc0
//       TR=1: fp8 e4m3 store, head-interleaved (byte idx = row*ldc0 + oc*4+h)
//   tiles [NLIN, NLIN+NSK) : out1 = A @ skip + bias1 (SKT store)
// ---------------------------------------------------------------------------
template <typename AT, typename SKT, int NLIN, int NSK, int TR>
__global__ __launch_bounds__(256) void gemm_fused_kernel(
    const AT* __restrict__ A, const __bf16* __restrict__ Bt,
    void* __restrict__ out0, int N0, int ldc0,
    const float* __restrict__ bias1, SKT* __restrict__ out1, int N1, int M) {
    __shared__ __bf16 As[64][136];    // [m][k], +8 pad (16B-aligned rows)
    __shared__ __bf16 Bs[64][136];    // [n][k]
    int tid = threadIdx.x;
    int m0 = blockIdx.x * 64;

    // stage A: 64 rows x 128 elems, 16B LDS writes (read once!)
#pragma unroll
    for (int rep = 0; rep < 4; ++rep) {
        int idx = tid + rep * 256;          // 0..1023
        int row = idx >> 4, seg = idx & 15; // 8-elem segment within row
        int gm = m0 + row;
        bf16x8 v = {};
        if (gm < M) {
            if constexpr (std::is_same<AT, float>::value) {
                const float* p = A + gm * KD + seg * 8;
                float4 f0 = *(const float4*)p;
                float4 f1 = *(const float4*)(p + 4);
                v[0] = (__bf16)f0.x; v[1] = (__bf16)f0.y; v[2] = (__bf16)f0.z; v[3] = (__bf16)f0.w;
                v[4] = (__bf16)f1.x; v[5] = (__bf16)f1.y; v[6] = (__bf16)f1.z; v[7] = (__bf16)f1.w;
            } else {
                v = *(const bf16x8*)(A + gm * KD + seg * 8);
            }
        }
        *(bf16x8*)&As[row][seg * 8] = v;
    }
    __syncthreads();

    int w = tid >> 6, lane = tid & 63;
    int lr = lane & 15, quad = lane >> 4;

#pragma unroll
    for (int t = 0; t < NLIN + NSK; ++t) {
        bool second = t >= NLIN;
        int N = second ? N1 : N0;
        int n0 = (second ? (t - NLIN) : t) * 64;
        if (t) __syncthreads();   // all waves done reading previous Bs
        // stage B tile: straight coalesced copy (Bt already [n][k] bf16, padded)
#pragma unroll
        for (int rep = 0; rep < 4; ++rep) {
            int idx = tid + rep * 256;          // 0..1023
            int row = idx >> 4, seg = idx & 15;
            *(bf16x8*)&Bs[row][seg * 8] =
                *(const bf16x8*)(Bt + ((t * 64 + row) << 7) + seg * 8);
        }
        __syncthreads();

        f32x4 acc[4] = {};
#pragma unroll
        for (int kc = 0; kc < 128; kc += 32) {
            bf16x8 a0 = *(const bf16x8*)&As[w * 16 + lr][kc + quad * 8];
            bf16x8 b0 = *(const bf16x8*)&Bs[lr][kc + quad * 8];
            bf16x8 b1 = *(const bf16x8*)&Bs[16 + lr][kc + quad * 8];
            bf16x8 b2 = *(const bf16x8*)&Bs[32 + lr][kc + quad * 8];
            bf16x8 b3 = *(const bf16x8*)&Bs[48 + lr][kc + quad * 8];
            acc[0] = __builtin_amdgcn_mfma_f32_16x16x32_bf16(a0, b0, acc[0], 0, 0, 0);
            acc[1] = __builtin_amdgcn_mfma_f32_16x16x32_bf16(a0, b1, acc[1], 0, 0, 0);
            acc[2] = __builtin_amdgcn_mfma_f32_16x16x32_bf16(a0, b2, acc[2], 0, 0, 0);
            acc[3] = __builtin_amdgcn_mfma_f32_16x16x32_bf16(a0, b3, acc[3], 0, 0, 0);
        }
        // epilogue: C/D layout col=lane&15, row=quad*4+reg
#pragma unroll
        for (int c = 0; c < 4; ++c) {
#pragma unroll
            for (int reg = 0; reg < 4; ++reg) {
                int row = m0 + w * 16 + quad * 4 + reg;
                int colg = n0 + c * 16 + lr;
                if (row < M && colg < N) {
                    float v = acc[c][reg];
                    if (second) {
                        v += bias1[colg];
                        out1[row * N + colg] = (SKT)v;
                    } else if (TR) {   // fp8, head-interleaved: byte = oc*4 + h
                        int h = (colg * 1395) >> 16;   // colg / 47 for colg<188
                        ((unsigned char*)out0)[row * ldc0 + (colg - 47 * h) * 4 + h] =
                            f32_to_fp8(v);
                    } else {
                        ((__bf16*)out0)[row * ldc0 + colg] = (__bf16)v;
                    }
                }
            }
        }
    }
}

// ---------------------------------------------------------------------------
// att for layers 0/1: 16 lanes per node (4 nodes/wave). Lane owns 8 feats =
// one head-quarter (head = l16>>2) -> single accumulator; 2-round reduce.
// ---------------------------------------------------------------------------
__global__ __launch_bounds__(256) void att_kernel(
    const __bf16* __restrict__ xh, const float* __restrict__ att_s,
    const float* __restrict__ att_d, float* __restrict__ a_src,
    float* __restrict__ a_dst, int n) {
    int tid = blockIdx.x * 256 + threadIdx.x;
    int node = tid >> 4;
    int l16 = threadIdx.x & 15;
    if (node >= n) return;
    uint4 q = ((const uint4*)xh)[node * 16 + l16];   // 8 bf16 feats
    int f0 = l16 * 8;
    float4 as0 = *(const float4*)(att_s + f0);
    float4 as1 = *(const float4*)(att_s + f0 + 4);
    float4 ad0 = *(const float4*)(att_d + f0);
    float4 ad1 = *(const float4*)(att_d + f0 + 4);
    float x0 = bflo_to_f(q.x), x1 = bfhi_to_f(q.x);
    float x2 = bflo_to_f(q.y), x3 = bfhi_to_f(q.y);
    float x4 = bflo_to_f(q.z), x5 = bfhi_to_f(q.z);
    float x6 = bflo_to_f(q.w), x7 = bfhi_to_f(q.w);
    float hs = x0 * as0.x + x1 * as0.y + x2 * as0.z + x3 * as0.w
             + x4 * as1.x + x5 * as1.y + x6 * as1.z + x7 * as1.w;
    float hd = x0 * ad0.x + x1 * ad0.y + x2 * ad0.z + x3 * ad0.w
             + x4 * ad1.x + x5 * ad1.y + x6 * ad1.z + x7 * ad1.w;
    hs += __shfl_xor(hs, 1, 64); hs += __shfl_xor(hs, 2, 64);
    hd += __shfl_xor(hd, 1, 64); hd += __shfl_xor(hd, 2, 64);
    if ((l16 & 3) == 0) {
        int h = l16 >> 2;
        a_src[node * 4 + h] = hs;
        a_dst[node * 4 + h] = hd;
    }
}

// ---------------------------------------------------------------------------
// att for layer 2 (fp8 head-interleaved xh, 192 B rows): lane<47 loads one
// uint = 4 heads of channel c=lane; per-head partials; 6-round butterfly.
// ---------------------------------------------------------------------------
__global__ __launch_bounds__(256) void att2_kernel(
    const unsigned char* __restrict__ xh8, const float* __restrict__ att_s,
    const float* __restrict__ att_d, float* __restrict__ a_src,
    float* __restrict__ a_dst, int n) {
    int node = (blockIdx.x * 256 + threadIdx.x) >> 6;
    int lane = threadIdx.x & 63;
    if (node >= n) return;
    float ps0 = 0.f, ps1 = 0.f, ps2 = 0.f, ps3 = 0.f;
    float pd0 = 0.f, pd1 = 0.f, pd2 = 0.f, pd3 = 0.f;
    if (lane < 47) {
        unsigned int q = ((const unsigned int*)(xh8 + node * NF2PB))[lane];
        float x0, x1, x2, x3;
        fp8x4_dec(q, x0, x1, x2, x3);
        ps0 = x0 * att_s[lane];       ps1 = x1 * att_s[47 + lane];
        ps2 = x2 * att_s[94 + lane];  ps3 = x3 * att_s[141 + lane];
        pd0 = x0 * att_d[lane];       pd1 = x1 * att_d[47 + lane];
        pd2 = x2 * att_d[94 + lane];  pd3 = x3 * att_d[141 + lane];
    }
#pragma unroll
    for (int off = 1; off <= 32; off <<= 1) {
        ps0 += __shfl_xor(ps0, off, 64); ps1 += __shfl_xor(ps1, off, 64);
        ps2 += __shfl_xor(ps2, off, 64); ps3 += __shfl_xor(ps3, off, 64);
        pd0 += __shfl_xor(pd0, off, 64); pd1 += __shfl_xor(pd1, off, 64);
        pd2 += __shfl_xor(pd2, off, 64); pd3 += __shfl_xor(pd3, off, 64);
    }
    if (lane < 4) {
        float vs = (lane == 0) ? ps0 : (lane == 1) ? ps1 : (lane == 2) ? ps2 : ps3;
        float vd = (lane == 0) ? pd0 : (lane == 1) ? pd1 : (lane == 2) ? pd2 : pd3;
        a_src[node * 4 + lane] = vs;
        a_dst[node * 4 + lane] = vd;
    }
}

// ---------------------------------------------------------------------------
// Aggregation: one wave per destination node. 32-bit indexing.
// No-max softmax (logits O(1-10); fp32 exp safe) — verified R10.
// MODE 0 (bf16 xh, 128 feats): half-wave per EDGE PAIR; lane fl owns feats
//   4fl..4fl+3. v_perm builds same-feat bf16 pairs from the two edges,
//   v_dot2_f32_bf16 with packed bf16 alpha-pair does 2 products/instr.
//   skip bf16, out bf16+ELU.
// MODE 1 (fp8 xh, 192 B rows, head-interleaved): lane c<47 loads uint =
//   4 heads of channel c; fp32 alphas; fp8dot. skip fp32, out fp32.
// ---------------------------------------------------------------------------
template <int MODE>
__global__ __launch_bounds__(256) void agg_kernel(
    const void* __restrict__ xhp, const float* __restrict__ a_src,
    const float* __restrict__ a_dst, const void* __restrict__ skipp,
    const float* __restrict__ bias, const int* __restrict__ row_ptr,
    const int* __restrict__ deg, const int* __restrict__ col,
    void* __restrict__ outp, int n) {
    __shared__ float s_af[4][64][4];      // MODE 1: f32 alphas
    __shared__ unsigned s_ap[4][32][4];   // MODE 0: packed bf16 alpha pairs [pair][head]
    __shared__ int s_j[4][64];
    int w = threadIdx.x >> 6;
    int lane = threadIdx.x & 63;
    int node = (blockIdx.x << 2) + w;
    bool active = node < n;
    int node_c = active ? node : 0;
    int start = row_ptr[node_c];
    int end = start + (active ? deg[node_c] : 0);
    float4 ad4 = *(const float4*)(a_dst + 4 * node_c);
    float adh[4] = {ad4.x, ad4.y, ad4.z, ad4.w};

    // ---- pass A: sum of exp per head (+ chunk-0 exp capture) ----
    int e0 = start + lane;
    bool ok0 = e0 < end;
    int jcap = ok0 ? col[e0] : 0;
    float evc[4];   // exp(leaky(e)) for this lane's chunk-0 edge
    {
        float4 as4 = *(const float4*)(a_src + 4 * jcap);
        float v0 = as4.x + adh[0]; v0 = v0 > 0.f ? v0 : 0.2f * v0;
        float v1 = as4.y + adh[1]; v1 = v1 > 0.f ? v1 : 0.2f * v1;
        float v2 = as4.z + adh[2]; v2 = v2 > 0.f ? v2 : 0.2f * v2;
        float v3 = as4.w + adh[3]; v3 = v3 > 0.f ? v3 : 0.2f * v3;
        evc[0] = ok0 ? __expf(v0) : 0.f;
        evc[1] = ok0 ? __expf(v1) : 0.f;
        evc[2] = ok0 ? __expf(v2) : 0.f;
        evc[3] = ok0 ? __expf(v3) : 0.f;
    }
    float s[4] = {evc[0], evc[1], evc[2], evc[3]};
    for (int e = e0 + 64; e < end; e += 64) {
        int j = col[e];
        float4 as4 = *(const float4*)(a_src + 4 * j);
        float ev[4] = {as4.x + adh[0], as4.y + adh[1], as4.z + adh[2], as4.w + adh[3]};
#pragma unroll
        for (int h = 0; h < 4; ++h) {
            float v = ev[h] > 0.f ? ev[h] : 0.2f * ev[h];
            s[h] += __expf(v);
        }
    }
#pragma unroll
    for (int off = 32; off >= 1; off >>= 1)
#pragma unroll
        for (int h = 0; h < 4; ++h) s[h] += __shfl_xor(s[h], off, 64);
    float inv[4];
#pragma unroll
    for (int h = 0; h < 4; ++h) inv[h] = 1.f / (s[h] + 1e-16f);

    // ---- pass B bookkeeping ----
    int half = lane >> 5, fl = lane & 31, myh2 = fl >> 3;
    bool lv = lane < 47;  // MODE 1 active lanes (channel c = lane)
    float acc0 = 0.f, acc1 = 0.f, acc2 = 0.f, acc3 = 0.f;
    const uint2* xb2 = (const uint2*)xhp;           // MODE 0
    const unsigned int* x8 = (const unsigned int*)xhp;  // MODE 1 (48 uints/row)

    auto run_chunk = [&](int cnt) {
        if constexpr (MODE == 0) {
            // edge-pair loop: half h walks pairs h, h+2, h+4, ...
            int npair = (cnt + 1) >> 1;
            int p = half;
            for (; p + 2 < npair; p += 4) {
                int2 j0 = *(const int2*)&s_j[w][2 * p];
                int2 j1 = *(const int2*)&s_j[w][2 * p + 4];
                unsigned ap0 = s_ap[w][p][myh2];
                unsigned ap1 = s_ap[w][p + 2][myh2];
                uint2 qa0 = xb2[(j0.x << 5) + fl];
                uint2 qb0 = xb2[(j0.y << 5) + fl];
                uint2 qa1 = xb2[(j1.x << 5) + fl];
                uint2 qb1 = xb2[(j1.y << 5) + fl];
                dot2bf(acc0, permb(qb0.x, qa0.x, 0x05040100u), ap0);
                dot2bf(acc1, permb(qb0.x, qa0.x, 0x07060302u), ap0);
                dot2bf(acc2, permb(qb0.y, qa0.y, 0x05040100u), ap0);
                dot2bf(acc3, permb(qb0.y, qa0.y, 0x07060302u), ap0);
                dot2bf(acc0, permb(qb1.x, qa1.x, 0x05040100u), ap1);
                dot2bf(acc1, permb(qb1.x, qa1.x, 0x07060302u), ap1);
                dot2bf(acc2, permb(qb1.y, qa1.y, 0x05040100u), ap1);
                dot2bf(acc3, permb(qb1.y, qa1.y, 0x07060302u), ap1);
            }
            for (; p < npair; p += 2) {
                int2 j0 = *(const int2*)&s_j[w][2 * p];
                unsigned ap0 = s_ap[w][p][myh2];
                uint2 qa0 = xb2[(j0.x << 5) + fl];
                uint2 qb0 = xb2[(j0.y << 5) + fl];
                dot2bf(acc0, permb(qb0.x, qa0.x, 0x05040100u), ap0);
                dot2bf(acc1, permb(qb0.x, qa0.x, 0x07060302u), ap0);
                dot2bf(acc2, permb(qb0.y, qa0.y, 0x05040100u), ap0);
                dot2bf(acc3, permb(qb0.y, qa0.y, 0x07060302u), ap0);
            }
        } else {
            int t = 0;
            for (; t + 7 < cnt; t += 8) {
                unsigned int q0 = lv ? x8[s_j[w][t] * 48 + lane] : 0u;
                unsigned int q1 = lv ? x8[s_j[w][t + 1] * 48 + lane] : 0u;
                unsigned int q2 = lv ? x8[s_j[w][t + 2] * 48 + lane] : 0u;
                unsigned int q3 = lv ? x8[s_j[w][t + 3] * 48 + lane] : 0u;
                unsigned int q4 = lv ? x8[s_j[w][t + 4] * 48 + lane] : 0u;
                unsigned int q5 = lv ? x8[s_j[w][t + 5] * 48 + lane] : 0u;
                unsigned int q6 = lv ? x8[s_j[w][t + 6] * 48 + lane] : 0u;
                unsigned int q7 = lv ? x8[s_j[w][t + 7] * 48 + lane] : 0u;
                acc0 = fp8dot(q0, *(const float4*)&s_af[w][t][0], acc0);
                acc0 = fp8dot(q1, *(const float4*)&s_af[w][t + 1][0], acc0);
                acc0 = fp8dot(q2, *(const float4*)&s_af[w][t + 2][0], acc0);
                acc0 = fp8dot(q3, *(const float4*)&s_af[w][t + 3][0], acc0);
                acc0 = fp8dot(q4, *(const float4*)&s_af[w][t + 4][0], acc0);
                acc0 = fp8dot(q5, *(const float4*)&s_af[w][t + 5][0], acc0);
                acc0 = fp8dot(q6, *(const float4*)&s_af[w][t + 6][0], acc0);
                acc0 = fp8dot(q7, *(const float4*)&s_af[w][t + 7][0], acc0);
            }
            for (; t + 3 < cnt; t += 4) {
                unsigned int q0 = lv ? x8[s_j[w][t] * 48 + lane] : 0u;
                unsigned int q1 = lv ? x8[s_j[w][t + 1] * 48 + lane] : 0u;
                unsigned int q2 = lv ? x8[s_j[w][t + 2] * 48 + lane] : 0u;
                unsigned int q3 = lv ? x8[s_j[w][t + 3] * 48 + lane] : 0u;
                acc0 = fp8dot(q0, *(const float4*)&s_af[w][t][0], acc0);
                acc0 = fp8dot(q1, *(const float4*)&s_af[w][t + 1][0], acc0);
                acc0 = fp8dot(q2, *(const float4*)&s_af[w][t + 2][0], acc0);
                acc0 = fp8dot(q3, *(const float4*)&s_af[w][t + 3][0], acc0);
            }
            for (; t < cnt; ++t) {
                unsigned int q = lv ? x8[s_j[w][t] * 48 + lane] : 0u;
                acc0 = fp8dot(q, *(const float4*)&s_af[w][t][0], acc0);
            }
        }
    };

    // chunk 0: reuse captured exp values, no col/a_src reload
    {
        float al[4];
#pragma unroll
        for (int h = 0; h < 4; ++h) al[h] = evc[h] * inv[h];
        s_j[w][lane] = jcap;
        if constexpr (MODE == 0) {
            float o0 = __shfl_xor(al[0], 1, 64);
            float o1 = __shfl_xor(al[1], 1, 64);
            float o2 = __shfl_xor(al[2], 1, 64);
            float o3 = __shfl_xor(al[3], 1, 64);
            if (!(lane & 1)) {
                uint4 pk = make_uint4(pk_bf(al[0], o0), pk_bf(al[1], o1),
                                      pk_bf(al[2], o2), pk_bf(al[3], o3));
                *(uint4*)&s_ap[w][lane >> 1][0] = pk;
            }
        } else {
            *(float4*)&s_af[w][lane][0] = make_float4(al[0], al[1], al[2], al[3]);
        }
        int cnt = end - start; if (cnt > 64) cnt = 64;
        run_chunk(cnt);
    }
    // remaining chunks (deg > 64: rare)
    for (int base = start + 64; base < end; base += 64) {
        int e = base + lane;
        bool ok = e < end;
        int jv = ok ? col[e] : 0;
        float4 as4 = *(const float4*)(a_src + 4 * jv);
        float asv[4] = {as4.x, as4.y, as4.z, as4.w};
        float al[4];
#pragma unroll
        for (int h = 0; h < 4; ++h) {
            float ev = asv[h] + adh[h];
            ev = ev > 0.f ? ev : 0.2f * ev;
            al[h] = ok ? __expf(ev) * inv[h] : 0.f;
        }
        s_j[w][lane] = jv;
        if constexpr (MODE == 0) {
            float o0 = __shfl_xor(al[0], 1, 64);
            float o1 = __shfl_xor(al[1], 1, 64);
            float o2 = __shfl_xor(al[2], 1, 64);
            float o3 = __shfl_xor(al[3], 1, 64);
            if (!(lane & 1)) {
                uint4 pk = make_uint4(pk_bf(al[0], o0), pk_bf(al[1], o1),
                                      pk_bf(al[2], o2), pk_bf(al[3], o3));
                *(uint4*)&s_ap[w][lane >> 1][0] = pk;
            }
        } else {
            *(float4*)&s_af[w][lane][0] = make_float4(al[0], al[1], al[2], al[3]);
        }
        int cnt = end - base; if (cnt > 64) cnt = 64;
        run_chunk(cnt);
    }

    if constexpr (MODE == 0) {
        // combine half-waves (each half accumulated its own pair subset)
        acc0 += __shfl_xor(acc0, 32, 64);
        acc1 += __shfl_xor(acc1, 32, 64);
        acc2 += __shfl_xor(acc2, 32, 64);
        acc3 += __shfl_xor(acc3, 32, 64);
        if (active && half == 0) {
            float4 bb = *(const float4*)(bias + 4 * fl);
            uint2 skq = ((const uint2*)skipp)[(node << 5) + fl];
            float v0 = acc0 + bb.x + bflo_to_f(skq.x);
            float v1 = acc1 + bb.y + bfhi_to_f(skq.x);
            float v2 = acc2 + bb.z + bflo_to_f(skq.y);
            float v3 = acc3 + bb.w + bfhi_to_f(skq.y);
            v0 = v0 > 0.f ? v0 : (__expf(v0) - 1.f);   // ELU
            v1 = v1 > 0.f ? v1 : (__expf(v1) - 1.f);
            v2 = v2 > 0.f ? v2 : (__expf(v2) - 1.f);
            v3 = v3 > 0.f ? v3 : (__expf(v3) - 1.f);
            uint2 o = make_uint2(pk_bf(v0, v1), pk_bf(v2, v3));
            ((uint2*)outp)[(node << 5) + fl] = o;
        }
    } else {
        if (active && lane < OUTC) {
            const float* skip = (const float*)skipp;
            float v = acc0 * 0.25f + bias[lane] + skip[node * OUTC + lane];
            ((float*)outp)[node * OUTC + lane] = v;
        }
    }
}

// ---------------------------------------------------------------------------
extern "C" void kernel_launch(void* const* d_in, const int* in_sizes, int n_in,
                              void* d_out, int out_size, void* d_ws, size_t ws_size,
                              hipStream_t stream) {
    const float* x        = (const float*)d_in[0];
    const int*   ei       = (const int*)d_in[1];
    const float* lin_w0   = (const float*)d_in[2];
    const float* att_src0 = (const float*)d_in[3];
    const float* att_dst0 = (const float*)d_in[4];
    const float* bias0    = (const float*)d_in[5];
    const float* skip_w0  = (const float*)d_in[6];
    const float* skip_b0  = (const float*)d_in[7];
    const float* lin_w1   = (const float*)d_in[8];
    const float* att_src1 = (const float*)d_in[9];
    const float* att_dst1 = (const float*)d_in[10];
    const float* bias1    = (const float*)d_in[11];
    const float* skip_w1  = (const float*)d_in[12];
    const float* skip_b1  = (const float*)d_in[13];
    const float* lin_w2   = (const float*)d_in[14];
    const float* att_src2 = (const float*)d_in[15];
    const float* att_dst2 = (const float*)d_in[16];
    const float* bias2    = (const float*)d_in[17];
    const float* skip_w2  = (const float*)d_in[18];
    const float* skip_b2  = (const float*)d_in[19];
    float* out = (float*)d_out;

    const int N = in_sizes[0] / KD;       // 50000
    const int E = in_sizes[1] / 2;        // 800000
    const int ET_ = E + N;                // with self loops

    char* ws = (char*)d_ws;
    size_t off = 0;
    auto alloc = [&](size_t bytes) -> void* {
        void* p = ws + off;
        off = (off + bytes + 255) & ~(size_t)255;
        return p;
    };
    void*   xh      = alloc((size_t)N * HC * 2 + 256);      // L0/1: bf16 128/row; L2: fp8 192B/row
    __bf16* buf_bf  = (__bf16*)alloc((size_t)N * HC * 2);   // ELU layer output (bf16)
    void*   skipbuf = alloc((size_t)N * HC * 4);            // skip: bf16 L0/1, fp32 L2
    float* a_src    = (float*)alloc((size_t)N * 4 * 4);
    float* a_dst    = (float*)alloc((size_t)N * 4 * 4);
    int* deg        = (int*)alloc((size_t)N * 4);
    int* row_ptr    = (int*)alloc((size_t)N * 4);
    int* fill       = (int*)alloc((size_t)N * 4);
    int* col        = (int*)alloc((size_t)ET_ * 4);
    int* counter    = (int*)alloc(256);
    __bf16* Bt      = (__bf16*)alloc((size_t)3 * 256 * 128 * 2);  // prepped weights

    // ---- weight prep (no deps; overlaps CSR build) ----
    prep_w_kernel<<<384, 256, 0, stream>>>(lin_w0, skip_w0, lin_w1, skip_w1,
                                           lin_w2, skip_w2, Bt);

    // ---- CSR build (dst-sorted adjacency, self-loops included) ----
    hipMemsetAsync(deg, 0, (size_t)N * 4, stream);
    hipMemsetAsync(counter, 0, 4, stream);
    int rngsz = (N + NPART - 1) / NPART;                 // 6250
    int cblocks = ((E + EPB - 1) / EPB) * NPART;         // 391 * 8
    count_kernel<<<cblocks, 256, 0, stream>>>(ei + E, deg, E, rngsz);
    scan_base_kernel<<<(N + 255) / 256, 256, 0, stream>>>(deg, counter, row_ptr, fill, col, N);
    fill_kernel<<<cblocks, 256, 0, stream>>>(ei, fill, col, E, rngsz);

    dim3 blk(256);
    int mblocks = (N + 63) / 64;          // BM=64
    int wave_blocks = (N + 3) / 4;        // one wave per node, 4 waves/block
    int att_blocks = (N * 16 + 255) / 256; // 16 threads per node

    // ---- layer 0 (A = fp32 x, converted in staging; skip bf16) ----
    gemm_fused_kernel<float, __bf16, 2, 2, 0><<<mblocks, blk, 0, stream>>>(
        x, Bt, xh, HC, HC, skip_b0, (__bf16*)skipbuf, HC, N);
    att_kernel<<<att_blocks, blk, 0, stream>>>((const __bf16*)xh, att_src0, att_dst0,
                                               a_src, a_dst, N);
    agg_kernel<0><<<wave_blocks, blk, 0, stream>>>(xh, a_src, a_dst, skipbuf, bias0,
                                                   row_ptr, deg, col, buf_bf, N);
    // ---- layer 1 (skip bf16) ----
    gemm_fused_kernel<__bf16, __bf16, 2, 2, 0><<<mblocks, blk, 0, stream>>>(
        buf_bf, Bt + 32768, xh, HC, HC, skip_b1, (__bf16*)skipbuf, HC, N);
    att_kernel<<<att_blocks, blk, 0, stream>>>((const __bf16*)xh, att_src1, att_dst1,
                                               a_src, a_dst, N);
    agg_kernel<0><<<wave_blocks, blk, 0, stream>>>(xh, a_src, a_dst, skipbuf, bias1,
                                                   row_ptr, deg, col, buf_bf, N);
    // ---- layer 2 (xh fp8 e4m3, head-interleaved, 192 B rows; skip fp32) ----
    gemm_fused_kernel<__bf16, float, 3, 1, 1><<<mblocks, blk, 0, stream>>>(
        buf_bf, Bt + 65536, xh, NF2, NF2PB, skip_b2, (float*)skipbuf, OUTC, N);
    att2_kernel<<<wave_blocks, blk, 0, stream>>>((const unsigned char*)xh, att_src2,
                                                 att_dst2, a_src, a_dst, N);
    agg_kernel<1><<<wave_blocks, blk, 0, stream>>>(xh, a_src, a_dst, skipbuf, bias2,
                                                   row_ptr, deg, col, out, N);
}

// Round 4
// 385.306 us; speedup vs baseline: 1.1848x; 1.0186x over previous
//
#include <hip/hip_runtime.h>
#include <math.h>
#include <type_traits>

// Problem constants (fixed by reference)
#define KD 128      // K dim of every GEMM (IN = HC = 128)
#define HC 128      // H*C for layers 0/1
#define NF2 188     // H*OUT for layer 2
#define NF2PB 192   // padded layer-2 row stride in BYTES (fp8: 3 cachelines)
#define OUTC 47

typedef __attribute__((ext_vector_type(8))) __bf16 bf16x8;
typedef __attribute__((ext_vector_type(4))) float f32x4;
typedef __attribute__((ext_vector_type(2))) float f32x2;

#ifdef __has_builtin
#if __has_builtin(__builtin_amdgcn_cvt_pk_f32_fp8)
#define HAVE_CVT_FP8_DEC 1
#endif
#if __has_builtin(__builtin_amdgcn_cvt_pk_fp8_f32)
#define HAVE_CVT_FP8_ENC 1
#endif
#endif

__device__ inline float bfhi_to_f(unsigned int u) {
    union { unsigned int u; float f; } c; c.u = u & 0xFFFF0000u; return c.f;
}
__device__ inline float bflo_to_f(unsigned int u) {
    union { unsigned int u; float f; } c; c.u = u << 16; return c.f;
}
__device__ inline unsigned short f_to_bfu(float f) {
    return __builtin_bit_cast(unsigned short, (__bf16)f);
}
__device__ inline unsigned int pk_bf(float a, float b) {
    return (unsigned int)f_to_bfu(a) | ((unsigned int)f_to_bfu(b) << 16);
}

// acc += x.lo*a.lo + x.hi*a.hi  (bf16 pairs, f32 accumulate) — VOP3P
__device__ inline void dot2bf(float& acc, unsigned int x, unsigned int a) {
    asm("v_dot2_f32_bf16 %0, %1, %2, %0" : "+v"(acc) : "v"(x), "v"(a));
}
// byte-select: result = bytes of (hi:lo) picked by sel
__device__ inline unsigned int permb(unsigned int hi, unsigned int lo, unsigned int sel) {
    return __builtin_amdgcn_perm(hi, lo, sel);
}

// ---- fp8 e4m3 helpers (HW cvt on gfx950; bit-math fallback) ----
#ifndef HAVE_CVT_FP8_DEC
__device__ inline float fp8_to_f32_b(unsigned int b) {
    int e = (b >> 3) & 15, m = b & 7;
    float v = e ? ldexpf((float)(8 + m), e - 10) : ldexpf((float)m, -9);
    return (b & 0x80) ? -v : v;
}
#endif
__device__ inline void fp8x4_dec(unsigned int q, float& a, float& b, float& c, float& d) {
#ifdef HAVE_CVT_FP8_DEC
    f32x2 lo = __builtin_amdgcn_cvt_pk_f32_fp8((int)q, false);
    f32x2 hi = __builtin_amdgcn_cvt_pk_f32_fp8((int)q, true);
    a = lo[0]; b = lo[1]; c = hi[0]; d = hi[1];
#else
    a = fp8_to_f32_b(q & 0xFF); b = fp8_to_f32_b((q >> 8) & 0xFF);
    c = fp8_to_f32_b((q >> 16) & 0xFF); d = fp8_to_f32_b((q >> 24) & 0xFF);
#endif
}
__device__ inline unsigned char f32_to_fp8(float v) {
#ifdef HAVE_CVT_FP8_ENC
    return (unsigned char)(__builtin_amdgcn_cvt_pk_fp8_f32(v, v, 0, false) & 0xFF);
#else
    unsigned u = __builtin_bit_cast(unsigned, v);
    unsigned s = (u >> 24) & 0x80;
    float a = fabsf(v);
    if (a < 0.0009765625f) return (unsigned char)s;
    if (a >= 448.f) return (unsigned char)(s | 0x7E);
    int e; float m = frexpf(a, &e);        // a = m*2^e, m in [0.5,1)
    int E = e - 1 + 7;
    int mi = (int)rintf(m * 16.f);         // in [8,16]
    if (mi == 16) { mi = 8; ++E; if (E >= 16) return (unsigned char)(s | 0x7E); }
    if (E <= 0) {
        int q = (int)rintf(a * 512.f); if (q > 7) q = 7;
        return (unsigned char)(s | q);
    }
    return (unsigned char)(s | (E << 3) | (mi - 8));
#endif
}
// acc += dot(4 fp8 of q, al)
__device__ inline float fp8dot(unsigned int q, float4 al, float acc) {
    float a, b, c, d;
    fp8x4_dec(q, a, b, c, d);
    return acc + al.x * a + al.y * b + al.z * c + al.w * d;
}

// ---------------------------------------------------------------------------
// CSR build: memset(deg,counter) -> count -> scan(+selfloop,+writeback) -> fill
// 8-way dst-range partitioning (R3 win): block b scans edge-chunk (b>>3),
// processes only dsts in range r = b&7 -> all writers of a col cacheline sit
// on one XCD -> no cross-XCD false-sharing write amplification.
// ---------------------------------------------------------------------------
#define NPART 8
#define EPB 2048   // edges per chunk (256 thr x 8)

__global__ __launch_bounds__(256) void count_kernel(
    const int* __restrict__ dst, int* deg, int e, int rngsz) {
    int r = blockIdx.x & (NPART - 1);
    int chunk = blockIdx.x / NPART;
    int base = chunk * EPB + threadIdx.x * 8;
    int lo = r * rngsz, hi = lo + rngsz;
    if (base >= e) return;
    if (base + 7 < e) {
        int4 d0 = *(const int4*)(dst + base);
        int4 d1 = *(const int4*)(dst + base + 4);
        int dd[8] = {d0.x, d0.y, d0.z, d0.w, d1.x, d1.y, d1.z, d1.w};
#pragma unroll
        for (int k = 0; k < 8; ++k)
            if (dd[k] >= lo && dd[k] < hi) atomicAdd(&deg[dd[k]], 1);
    } else {
        for (int k = base; k < e; ++k) {
            int d = dst[k];
            if (d >= lo && d < hi) atomicAdd(&deg[d], 1);
        }
    }
}

__global__ __launch_bounds__(256) void scan_base_kernel(
    int* __restrict__ deg, int* counter,
    int* __restrict__ row_ptr, int* __restrict__ fill, int* __restrict__ col, int n) {
    int i = blockIdx.x * 256 + threadIdx.x;
    int v = (i < n) ? (deg[i] + 1) : 0;
    int lane = threadIdx.x & 63, w = threadIdx.x >> 6;
    int incl = v;
#pragma unroll
    for (int off = 1; off < 64; off <<= 1) {
        int u = __shfl_up(incl, off, 64);
        if (lane >= off) incl += u;
    }
    __shared__ int wsum[4];
    __shared__ int base_sh;
    if (lane == 63) wsum[w] = incl;
    __syncthreads();
    if (threadIdx.x == 0)
        base_sh = atomicAdd(counter, wsum[0] + wsum[1] + wsum[2] + wsum[3]);
    int woff = 0;
    for (int k = 0; k < w; ++k) woff += wsum[k];
    __syncthreads();
    int excl = base_sh + woff + incl - v;
    if (i < n) {
        row_ptr[i] = excl;
        col[excl] = i;        // self-loop at segment head
        fill[i] = excl + 1;   // edges fill after it
        deg[i] = v;           // write back incl. self-loop
    }
}

__global__ __launch_bounds__(256) void fill_kernel(
    const int* __restrict__ ei, int* fill, int* col, int e, int rngsz) {
    int r = blockIdx.x & (NPART - 1);
    int chunk = blockIdx.x / NPART;
    int base = chunk * EPB + threadIdx.x * 8;
    int lo = r * rngsz, hi = lo + rngsz;
    if (base >= e) return;
    const int* dstp = ei + e;
    if (base + 7 < e) {
        int4 d0 = *(const int4*)(dstp + base);
        int4 d1 = *(const int4*)(dstp + base + 4);
        int dd[8] = {d0.x, d0.y, d0.z, d0.w, d1.x, d1.y, d1.z, d1.w};
#pragma unroll
        for (int k = 0; k < 8; ++k) {
            if (dd[k] >= lo && dd[k] < hi) {
                int pos = atomicAdd(&fill[dd[k]], 1);
                col[pos] = ei[base + k];
            }
        }
    } else {
        for (int k = base; k < e; ++k) {
            int d = dstp[k];
            if (d >= lo && d < hi) {
                int pos = atomicAdd(&fill[d], 1);
                col[pos] = ei[k];
            }
        }
    }
}

// ---------------------------------------------------------------------------
// One-shot weight prep: transpose + convert all 6 weight matrices into padded
// bf16 [n][k] buffers (64-row-aligned tiles, zero rows past true N).
//   Bt layout per layer L (256 rows x 128 k):
//     L0/L1: rows 0..127 = lin_w^T, 128..255 = skip_w^T
//     L2:    rows 0..187 = lin_w2^T, 188..191 = 0, 192..238 = skip_w2^T, rest 0
// ---------------------------------------------------------------------------
__global__ __launch_bounds__(256) void prep_w_kernel(
    const float* __restrict__ lw0, const float* __restrict__ sw0,
    const float* __restrict__ lw1, const float* __restrict__ sw1,
    const float* __restrict__ lw2, const float* __restrict__ sw2,
    __bf16* __restrict__ bt) {
    int idx = blockIdx.x * 256 + threadIdx.x;   // 3 * 256 * 128 = 98304 total
    int buf = idx >> 15;                        // / 32768
    int r = idx & 32767;
    int n = r >> 7, k = r & 127;
    float v = 0.f;
    if (buf == 0) v = (n < 128) ? lw0[k * 128 + n] : sw0[k * 128 + n - 128];
    else if (buf == 1) v = (n < 128) ? lw1[k * 128 + n] : sw1[k * 128 + n - 128];
    else {
        if (n < 188) v = lw2[k * 188 + n];
        else if (n >= 192 && n < 239) v = sw2[k * 47 + n - 192];
    }
    bt[idx] = (__bf16)v;
}

// ---------------------------------------------------------------------------
// Fused bf16 MFMA GEMM: A staged ONCE per block (BM=64); B tile staged to LDS
// per column tile as a STRAIGHT bf16x8 memcpy from the prepped [n][k] buffer.
//   tiles [0, NLIN)        : out0 = A @ lin
//       TR=0: bf16 store, elem stride ldc0
//       TR=1: fp8 e4m3 store, head-interleaved (byte idx = row*ldc0 + oc*4+h)
//   tiles [NLIN, NLIN+NSK) : out1 = A @ skip + bias1 (SKT store)
// ---------------------------------------------------------------------------
template <typename AT, typename SKT, int NLIN, int NSK, int TR>
__global__ __launch_bounds__(256) void gemm_fused_kernel(
    const AT* __restrict__ A, const __bf16* __restrict__ Bt,
    void* __restrict__ out0, int N0, int ldc0,
    const float* __restrict__ bias1, SKT* __restrict__ out1, int N1, int M) {
    __shared__ __bf16 As[64][136];    // [m][k], +8 pad (16B-aligned rows)
    __shared__ __bf16 Bs[64][136];    // [n][k]
    int tid = threadIdx.x;
    int m0 = blockIdx.x * 64;

    // stage A: 64 rows x 128 elems, 16B LDS writes (read once!)
#pragma unroll
    for (int rep = 0; rep < 4; ++rep) {
        int idx = tid + rep * 256;          // 0..1023
        int row = idx >> 4, seg = idx & 15; // 8-elem segment within row
        int gm = m0 + row;
        bf16x8 v = {};
        if (gm < M) {
            if constexpr (std::is_same<AT, float>::value) {
                const float* p = A + gm * KD + seg * 8;
                float4 f0 = *(const float4*)p;
                float4 f1 = *(const float4*)(p + 4);
                v[0] = (__bf16)f0.x; v[1] = (__bf16)f0.y; v[2] = (__bf16)f0.z; v[3] = (__bf16)f0.w;
                v[4] = (__bf16)f1.x; v[5] = (__bf16)f1.y; v[6] = (__bf16)f1.z; v[7] = (__bf16)f1.w;
            } else {
                v = *(const bf16x8*)(A + gm * KD + seg * 8);
            }
        }
        *(bf16x8*)&As[row][seg * 8] = v;
    }
    __syncthreads();

    int w = tid >> 6, lane = tid & 63;
    int lr = lane & 15, quad = lane >> 4;

#pragma unroll
    for (int t = 0; t < NLIN + NSK; ++t) {
        bool second = t >= NLIN;
        int N = second ? N1 : N0;
        int n0 = (second ? (t - NLIN) : t) * 64;
        if (t) __syncthreads();   // all waves done reading previous Bs
        // stage B tile: straight coalesced copy (Bt already [n][k] bf16, padded)
#pragma unroll
        for (int rep = 0; rep < 4; ++rep) {
            int idx = tid + rep * 256;          // 0..1023
            int row = idx >> 4, seg = idx & 15;
            *(bf16x8*)&Bs[row][seg * 8] =
                *(const bf16x8*)(Bt + ((t * 64 + row) << 7) + seg * 8);
        }
        __syncthreads();

        f32x4 acc[4] = {};
#pragma unroll
        for (int kc = 0; kc < 128; kc += 32) {
            bf16x8 a0 = *(const bf16x8*)&As[w * 16 + lr][kc + quad * 8];
            bf16x8 b0 = *(const bf16x8*)&Bs[lr][kc + quad * 8];
            bf16x8 b1 = *(const bf16x8*)&Bs[16 + lr][kc + quad * 8];
            bf16x8 b2 = *(const bf16x8*)&Bs[32 + lr][kc + quad * 8];
            bf16x8 b3 = *(const bf16x8*)&Bs[48 + lr][kc + quad * 8];
            acc[0] = __builtin_amdgcn_mfma_f32_16x16x32_bf16(a0, b0, acc[0], 0, 0, 0);
            acc[1] = __builtin_amdgcn_mfma_f32_16x16x32_bf16(a0, b1, acc[1], 0, 0, 0);
            acc[2] = __builtin_amdgcn_mfma_f32_16x16x32_bf16(a0, b2, acc[2], 0, 0, 0);
            acc[3] = __builtin_amdgcn_mfma_f32_16x16x32_bf16(a0, b3, acc[3], 0, 0, 0);
        }
        // epilogue: C/D layout col=lane&15, row=quad*4+reg
#pragma unroll
        for (int c = 0; c < 4; ++c) {
#pragma unroll
            for (int reg = 0; reg < 4; ++reg) {
                int row = m0 + w * 16 + quad * 4 + reg;
                int colg = n0 + c * 16 + lr;
                if (row < M && colg < N) {
                    float v = acc[c][reg];
                    if (second) {
                        v += bias1[colg];
                        out1[row * N + colg] = (SKT)v;
                    } else if (TR) {   // fp8, head-interleaved: byte = oc*4 + h
                        int h = (colg * 1395) >> 16;   // colg / 47 for colg<188
                        ((unsigned char*)out0)[row * ldc0 + (colg - 47 * h) * 4 + h] =
                            f32_to_fp8(v);
                    } else {
                        ((__bf16*)out0)[row * ldc0 + colg] = (__bf16)v;
                    }
                }
            }
        }
    }
}

// ---------------------------------------------------------------------------
// att for layers 0/1: 16 lanes per node (4 nodes/wave). Lane owns 8 feats =
// one head-quarter (head = l16>>2) -> single accumulator; 2-round reduce.
// ---------------------------------------------------------------------------
__global__ __launch_bounds__(256) void att_kernel(
    const __bf16* __restrict__ xh, const float* __restrict__ att_s,
    const float* __restrict__ att_d, float* __restrict__ a_src,
    float* __restrict__ a_dst, int n) {
    int tid = blockIdx.x * 256 + threadIdx.x;
    int node = tid >> 4;
    int l16 = threadIdx.x & 15;
    if (node >= n) return;
    uint4 q = ((const uint4*)xh)[node * 16 + l16];   // 8 bf16 feats
    int f0 = l16 * 8;
    float4 as0 = *(const float4*)(att_s + f0);
    float4 as1 = *(const float4*)(att_s + f0 + 4);
    float4 ad0 = *(const float4*)(att_d + f0);
    float4 ad1 = *(const float4*)(att_d + f0 + 4);
    float x0 = bflo_to_f(q.x), x1 = bfhi_to_f(q.x);
    float x2 = bflo_to_f(q.y), x3 = bfhi_to_f(q.y);
    float x4 = bflo_to_f(q.z), x5 = bfhi_to_f(q.z);
    float x6 = bflo_to_f(q.w), x7 = bfhi_to_f(q.w);
    float hs = x0 * as0.x + x1 * as0.y + x2 * as0.z + x3 * as0.w
             + x4 * as1.x + x5 * as1.y + x6 * as1.z + x7 * as1.w;
    float hd = x0 * ad0.x + x1 * ad0.y + x2 * ad0.z + x3 * ad0.w
             + x4 * ad1.x + x5 * ad1.y + x6 * ad1.z + x7 * ad1.w;
    hs += __shfl_xor(hs, 1, 64); hs += __shfl_xor(hs, 2, 64);
    hd += __shfl_xor(hd, 1, 64); hd += __shfl_xor(hd, 2, 64);
    if ((l16 & 3) == 0) {
        int h = l16 >> 2;
        a_src[node * 4 + h] = hs;
        a_dst[node * 4 + h] = hd;
    }
}

// ---------------------------------------------------------------------------
// att for layer 2 (fp8 head-interleaved xh, 192 B rows): lane<47 loads one
// uint = 4 heads of channel c=lane; per-head partials; 6-round butterfly.
// ---------------------------------------------------------------------------
__global__ __launch_bounds__(256) void att2_kernel(
    const unsigned char* __restrict__ xh8, const float* __restrict__ att_s,
    const float* __restrict__ att_d, float* __restrict__ a_src,
    float* __restrict__ a_dst, int n) {
    int node = (blockIdx.x * 256 + threadIdx.x) >> 6;
    int lane = threadIdx.x & 63;
    if (node >= n) return;
    float ps0 = 0.f, ps1 = 0.f, ps2 = 0.f, ps3 = 0.f;
    float pd0 = 0.f, pd1 = 0.f, pd2 = 0.f, pd3 = 0.f;
    if (lane < 47) {
        unsigned int q = ((const unsigned int*)(xh8 + node * NF2PB))[lane];
        float x0, x1, x2, x3;
        fp8x4_dec(q, x0, x1, x2, x3);
        ps0 = x0 * att_s[lane];       ps1 = x1 * att_s[47 + lane];
        ps2 = x2 * att_s[94 + lane];  ps3 = x3 * att_s[141 + lane];
        pd0 = x0 * att_d[lane];       pd1 = x1 * att_d[47 + lane];
        pd2 = x2 * att_d[94 + lane];  pd3 = x3 * att_d[141 + lane];
    }
#pragma unroll
    for (int off = 1; off <= 32; off <<= 1) {
        ps0 += __shfl_xor(ps0, off, 64); ps1 += __shfl_xor(ps1, off, 64);
        ps2 += __shfl_xor(ps2, off, 64); ps3 += __shfl_xor(ps3, off, 64);
        pd0 += __shfl_xor(pd0, off, 64); pd1 += __shfl_xor(pd1, off, 64);
        pd2 += __shfl_xor(pd2, off, 64); pd3 += __shfl_xor(pd3, off, 64);
    }
    if (lane < 4) {
        float vs = (lane == 0) ? ps0 : (lane == 1) ? ps1 : (lane == 2) ? ps2 : ps3;
        float vd = (lane == 0) ? pd0 : (lane == 1) ? pd1 : (lane == 2) ? pd2 : pd3;
        a_src[node * 4 + lane] = vs;
        a_dst[node * 4 + lane] = vd;
    }
}

// ---------------------------------------------------------------------------
// agg for layers 0/1 (bf16 xh): 16 LANES PER NODE, 16 nodes per 256-block.
// R3 post-mortem: avg deg = 17 << 64 — the 64-lane-per-node version spent
// most of its time on per-node fixed cost (full-width pass A, 24-round
// butterfly, epilogue) with 47/64 lanes padding. 16-lane groups amortize one
// instruction stream over 4 nodes/wave and halve gather instruction count
// (uint4/lane = 8 feats). exps of the first TWO 16-edge chunks are captured
// in registers (covers deg<=32; recompute beyond — rare).
// ---------------------------------------------------------------------------
__global__ __launch_bounds__(256) void agg0_kernel(
    const uint4* __restrict__ xh, const float* __restrict__ a_src,
    const float* __restrict__ a_dst, const uint4* __restrict__ skipb,
    const float* __restrict__ bias, const int* __restrict__ row_ptr,
    const int* __restrict__ deg, const int* __restrict__ col,
    uint4* __restrict__ outp, int n) {
    __shared__ int s_j[16][16];
    __shared__ unsigned s_ap[16][8][4];   // [grp][pair][head] packed bf16 alpha pairs
    int grp = threadIdx.x >> 4;           // 0..15
    int l16 = threadIdx.x & 15;
    int node = (blockIdx.x << 4) + grp;
    bool active = node < n;
    int node_c = active ? node : 0;
    int start = row_ptr[node_c];
    int end = start + (active ? deg[node_c] : 0);
    float4 ad4 = *(const float4*)(a_dst + 4 * node_c);

    // ---- pass A: sum of exp per head; capture chunk 0/1 exps ----
    float s0 = 0.f, s1 = 0.f, s2 = 0.f, s3 = 0.f;
    float e00 = 0.f, e01 = 0.f, e02 = 0.f, e03 = 0.f;
    float e10 = 0.f, e11 = 0.f, e12 = 0.f, e13 = 0.f;
    int jc0 = 0, jc1 = 0;
    int c = 0;
    for (int base = start; base < end; base += 16, ++c) {
        int e = base + l16;
        bool ok = e < end;
        int j = ok ? col[e] : 0;
        float4 as4 = *(const float4*)(a_src + 4 * j);
        float v0 = as4.x + ad4.x; v0 = v0 > 0.f ? v0 : 0.2f * v0;
        float v1 = as4.y + ad4.y; v1 = v1 > 0.f ? v1 : 0.2f * v1;
        float v2 = as4.z + ad4.z; v2 = v2 > 0.f ? v2 : 0.2f * v2;
        float v3 = as4.w + ad4.w; v3 = v3 > 0.f ? v3 : 0.2f * v3;
        float x0 = ok ? __expf(v0) : 0.f;
        float x1 = ok ? __expf(v1) : 0.f;
        float x2 = ok ? __expf(v2) : 0.f;
        float x3 = ok ? __expf(v3) : 0.f;
        s0 += x0; s1 += x1; s2 += x2; s3 += x3;
        if (c == 0) { jc0 = j; e00 = x0; e01 = x1; e02 = x2; e03 = x3; }
        else if (c == 1) { jc1 = j; e10 = x0; e11 = x1; e12 = x2; e13 = x3; }
    }
#pragma unroll
    for (int off = 1; off <= 8; off <<= 1) {
        s0 += __shfl_xor(s0, off, 64);
        s1 += __shfl_xor(s1, off, 64);
        s2 += __shfl_xor(s2, off, 64);
        s3 += __shfl_xor(s3, off, 64);
    }
    float i0 = 1.f / (s0 + 1e-16f), i1 = 1.f / (s1 + 1e-16f);
    float i2 = 1.f / (s2 + 1e-16f), i3 = 1.f / (s3 + 1e-16f);

    // ---- pass B: gather + weighted accumulate (lane owns feats 8*l16..+7) ----
    int myh = l16 >> 2;
    float a0 = 0.f, a1 = 0.f, a2 = 0.f, a3 = 0.f;
    float a4 = 0.f, a5 = 0.f, a6 = 0.f, a7 = 0.f;
    c = 0;
    for (int base = start; base < end; base += 16, ++c) {
        float al0, al1, al2, al3; int jv;
        if (c == 0) {
            jv = jc0; al0 = e00 * i0; al1 = e01 * i1; al2 = e02 * i2; al3 = e03 * i3;
        } else if (c == 1) {
            jv = jc1; al0 = e10 * i0; al1 = e11 * i1; al2 = e12 * i2; al3 = e13 * i3;
        } else {  // deg > 32: rare — recompute
            int e = base + l16;
            bool ok = e < end;
            jv = ok ? col[e] : 0;
            float4 as4 = *(const float4*)(a_src + 4 * jv);
            float v0 = as4.x + ad4.x; v0 = v0 > 0.f ? v0 : 0.2f * v0;
            float v1 = as4.y + ad4.y; v1 = v1 > 0.f ? v1 : 0.2f * v1;
            float v2 = as4.z + ad4.z; v2 = v2 > 0.f ? v2 : 0.2f * v2;
            float v3 = as4.w + ad4.w; v3 = v3 > 0.f ? v3 : 0.2f * v3;
            al0 = ok ? __expf(v0) * i0 : 0.f;
            al1 = ok ? __expf(v1) * i1 : 0.f;
            al2 = ok ? __expf(v2) * i2 : 0.f;
            al3 = ok ? __expf(v3) * i3 : 0.f;
        }
        s_j[grp][l16] = jv;
        float o0 = __shfl_xor(al0, 1, 64);
        float o1 = __shfl_xor(al1, 1, 64);
        float o2 = __shfl_xor(al2, 1, 64);
        float o3 = __shfl_xor(al3, 1, 64);
        if (!(l16 & 1)) {
            *(uint4*)&s_ap[grp][l16 >> 1][0] =
                make_uint4(pk_bf(al0, o0), pk_bf(al1, o1), pk_bf(al2, o2), pk_bf(al3, o3));
        }
        int cnt = end - base; if (cnt > 16) cnt = 16;
        int npair = (cnt + 1) >> 1;
        int p = 0;
        for (; p + 1 < npair; p += 2) {
            int2 jpa = *(const int2*)&s_j[grp][2 * p];
            int2 jpb = *(const int2*)&s_j[grp][2 * p + 2];
            unsigned apa = s_ap[grp][p][myh];
            unsigned apb = s_ap[grp][p + 1][myh];
            uint4 qa0 = xh[jpa.x * 16 + l16];
            uint4 qb0 = xh[jpa.y * 16 + l16];
            uint4 qa1 = xh[jpb.x * 16 + l16];
            uint4 qb1 = xh[jpb.y * 16 + l16];
            dot2bf(a0, permb(qb0.x, qa0.x, 0x05040100u), apa);
            dot2bf(a1, permb(qb0.x, qa0.x, 0x07060302u), apa);
            dot2bf(a2, permb(qb0.y, qa0.y, 0x05040100u), apa);
            dot2bf(a3, permb(qb0.y, qa0.y, 0x07060302u), apa);
            dot2bf(a4, permb(qb0.z, qa0.z, 0x05040100u), apa);
            dot2bf(a5, permb(qb0.z, qa0.z, 0x07060302u), apa);
            dot2bf(a6, permb(qb0.w, qa0.w, 0x05040100u), apa);
            dot2bf(a7, permb(qb0.w, qa0.w, 0x07060302u), apa);
            dot2bf(a0, permb(qb1.x, qa1.x, 0x05040100u), apb);
            dot2bf(a1, permb(qb1.x, qa1.x, 0x07060302u), apb);
            dot2bf(a2, permb(qb1.y, qa1.y, 0x05040100u), apb);
            dot2bf(a3, permb(qb1.y, qa1.y, 0x07060302u), apb);
            dot2bf(a4, permb(qb1.z, qa1.z, 0x05040100u), apb);
            dot2bf(a5, permb(qb1.z, qa1.z, 0x07060302u), apb);
            dot2bf(a6, permb(qb1.w, qa1.w, 0x05040100u), apb);
            dot2bf(a7, permb(qb1.w, qa1.w, 0x07060302u), apb);
        }
        for (; p < npair; ++p) {
            int2 jp = *(const int2*)&s_j[grp][2 * p];
            unsigned ap = s_ap[grp][p][myh];
            uint4 qa = xh[jp.x * 16 + l16];
            uint4 qb = xh[jp.y * 16 + l16];
            dot2bf(a0, permb(qb.x, qa.x, 0x05040100u), ap);
            dot2bf(a1, permb(qb.x, qa.x, 0x07060302u), ap);
            dot2bf(a2, permb(qb.y, qa.y, 0x05040100u), ap);
            dot2bf(a3, permb(qb.y, qa.y, 0x07060302u), ap);
            dot2bf(a4, permb(qb.z, qa.z, 0x05040100u), ap);
            dot2bf(a5, permb(qb.z, qa.z, 0x07060302u), ap);
            dot2bf(a6, permb(qb.w, qa.w, 0x05040100u), ap);
            dot2bf(a7, permb(qb.w, qa.w, 0x07060302u), ap);
        }
    }

    // ---- epilogue: + bias + skip, ELU, bf16 store (16 B/lane) ----
    if (active) {
        float4 b0 = *(const float4*)(bias + 8 * l16);
        float4 b1 = *(const float4*)(bias + 8 * l16 + 4);
        uint4 skq = skipb[node * 16 + l16];
        float v0 = a0 + b0.x + bflo_to_f(skq.x);
        float v1 = a1 + b0.y + bfhi_to_f(skq.x);
        float v2 = a2 + b0.z + bflo_to_f(skq.y);
        float v3 = a3 + b0.w + bfhi_to_f(skq.y);
        float v4 = a4 + b1.x + bflo_to_f(skq.z);
        float v5 = a5 + b1.y + bfhi_to_f(skq.z);
        float v6 = a6 + b1.z + bflo_to_f(skq.w);
        float v7 = a7 + b1.w + bfhi_to_f(skq.w);
        v0 = v0 > 0.f ? v0 : (__expf(v0) - 1.f);
        v1 = v1 > 0.f ? v1 : (__expf(v1) - 1.f);
        v2 = v2 > 0.f ? v2 : (__expf(v2) - 1.f);
        v3 = v3 > 0.f ? v3 : (__expf(v3) - 1.f);
        v4 = v4 > 0.f ? v4 : (__expf(v4) - 1.f);
        v5 = v5 > 0.f ? v5 : (__expf(v5) - 1.f);
        v6 = v6 > 0.f ? v6 : (__expf(v6) - 1.f);
        v7 = v7 > 0.f ? v7 : (__expf(v7) - 1.f);
        outp[node * 16 + l16] =
            make_uint4(pk_bf(v0, v1), pk_bf(v2, v3), pk_bf(v4, v5), pk_bf(v6, v7));
    }
}

// ---------------------------------------------------------------------------
// agg for layer 2 (fp8 xh, 192 B rows, head-interleaved): one wave per node.
// lane c<47 loads uint = 4 heads of channel c; fp32 alphas via LDS; fp8dot.
// ---------------------------------------------------------------------------
__global__ __launch_bounds__(256) void agg1_kernel(
    const unsigned int* __restrict__ x8, const float* __restrict__ a_src,
    const float* __restrict__ a_dst, const float* __restrict__ skip,
    const float* __restrict__ bias, const int* __restrict__ row_ptr,
    const int* __restrict__ deg, const int* __restrict__ col,
    float* __restrict__ outp, int n) {
    __shared__ float s_af[4][64][4];
    __shared__ int s_j[4][64];
    int w = threadIdx.x >> 6;
    int lane = threadIdx.x & 63;
    int node = (blockIdx.x << 2) + w;
    bool active = node < n;
    int node_c = active ? node : 0;
    int start = row_ptr[node_c];
    int end = start + (active ? deg[node_c] : 0);
    float4 ad4 = *(const float4*)(a_dst + 4 * node_c);
    float adh[4] = {ad4.x, ad4.y, ad4.z, ad4.w};

    int e0 = start + lane;
    bool ok0 = e0 < end;
    int jcap = ok0 ? col[e0] : 0;
    float evc[4];
    {
        float4 as4 = *(const float4*)(a_src + 4 * jcap);
        float v0 = as4.x + adh[0]; v0 = v0 > 0.f ? v0 : 0.2f * v0;
        float v1 = as4.y + adh[1]; v1 = v1 > 0.f ? v1 : 0.2f * v1;
        float v2 = as4.z + adh[2]; v2 = v2 > 0.f ? v2 : 0.2f * v2;
        float v3 = as4.w + adh[3]; v3 = v3 > 0.f ? v3 : 0.2f * v3;
        evc[0] = ok0 ? __expf(v0) : 0.f;
        evc[1] = ok0 ? __expf(v1) : 0.f;
        evc[2] = ok0 ? __expf(v2) : 0.f;
        evc[3] = ok0 ? __expf(v3) : 0.f;
    }
    float s[4] = {evc[0], evc[1], evc[2], evc[3]};
    for (int e = e0 + 64; e < end; e += 64) {
        int j = col[e];
        float4 as4 = *(const float4*)(a_src + 4 * j);
        float ev[4] = {as4.x + adh[0], as4.y + adh[1], as4.z + adh[2], as4.w + adh[3]};
#pragma unroll
        for (int h = 0; h < 4; ++h) {
            float v = ev[h] > 0.f ? ev[h] : 0.2f * ev[h];
            s[h] += __expf(v);
        }
    }
#pragma unroll
    for (int off = 32; off >= 1; off >>= 1)
#pragma unroll
        for (int h = 0; h < 4; ++h) s[h] += __shfl_xor(s[h], off, 64);
    float inv[4];
#pragma unroll
    for (int h = 0; h < 4; ++h) inv[h] = 1.f / (s[h] + 1e-16f);

    bool lv = lane < 47;
    float acc0 = 0.f;

    auto run_chunk = [&](int cnt) {
        int t = 0;
        for (; t + 7 < cnt; t += 8) {
            unsigned int q0 = lv ? x8[s_j[w][t] * 48 + lane] : 0u;
            unsigned int q1 = lv ? x8[s_j[w][t + 1] * 48 + lane] : 0u;
            unsigned int q2 = lv ? x8[s_j[w][t + 2] * 48 + lane] : 0u;
            unsigned int q3 = lv ? x8[s_j[w][t + 3] * 48 + lane] : 0u;
            unsigned int q4 = lv ? x8[s_j[w][t + 4] * 48 + lane] : 0u;
            unsigned int q5 = lv ? x8[s_j[w][t + 5] * 48 + lane] : 0u;
            unsigned int q6 = lv ? x8[s_j[w][t + 6] * 48 + lane] : 0u;
            unsigned int q7 = lv ? x8[s_j[w][t + 7] * 48 + lane] : 0u;
            acc0 = fp8dot(q0, *(const float4*)&s_af[w][t][0], acc0);
            acc0 = fp8dot(q1, *(const float4*)&s_af[w][t + 1][0], acc0);
            acc0 = fp8dot(q2, *(const float4*)&s_af[w][t + 2][0], acc0);
            acc0 = fp8dot(q3, *(const float4*)&s_af[w][t + 3][0], acc0);
            acc0 = fp8dot(q4, *(const float4*)&s_af[w][t + 4][0], acc0);
            acc0 = fp8dot(q5, *(const float4*)&s_af[w][t + 5][0], acc0);
            acc0 = fp8dot(q6, *(const float4*)&s_af[w][t + 6][0], acc0);
            acc0 = fp8dot(q7, *(const float4*)&s_af[w][t + 7][0], acc0);
        }
        for (; t + 3 < cnt; t += 4) {
            unsigned int q0 = lv ? x8[s_j[w][t] * 48 + lane] : 0u;
            unsigned int q1 = lv ? x8[s_j[w][t + 1] * 48 + lane] : 0u;
            unsigned int q2 = lv ? x8[s_j[w][t + 2] * 48 + lane] : 0u;
            unsigned int q3 = lv ? x8[s_j[w][t + 3] * 48 + lane] : 0u;
            acc0 = fp8dot(q0, *(const float4*)&s_af[w][t][0], acc0);
            acc0 = fp8dot(q1, *(const float4*)&s_af[w][t + 1][0], acc0);
            acc0 = fp8dot(q2, *(const float4*)&s_af[w][t + 2][0], acc0);
            acc0 = fp8dot(q3, *(const float4*)&s_af[w][t + 3][0], acc0);
        }
        for (; t < cnt; ++t) {
            unsigned int q = lv ? x8[s_j[w][t] * 48 + lane] : 0u;
            acc0 = fp8dot(q, *(const float4*)&s_af[w][t][0], acc0);
        }
    };

    {
        float al[4];
#pragma unroll
        for (int h = 0; h < 4; ++h) al[h] = evc[h] * inv[h];
        s_j[w][lane] = jcap;
        *(float4*)&s_af[w][lane][0] = make_float4(al[0], al[1], al[2], al[3]);
        int cnt = end - start; if (cnt > 64) cnt = 64;
        run_chunk(cnt);
    }
    for (int base = start + 64; base < end; base += 64) {
        int e = base + lane;
        bool ok = e < end;
        int jv = ok ? col[e] : 0;
        float4 as4 = *(const float4*)(a_src + 4 * jv);
        float al[4];
#pragma unroll
        for (int h = 0; h < 4; ++h) {
            float ev = ((const float*)&as4)[h] + adh[h];
            ev = ev > 0.f ? ev : 0.2f * ev;
            al[h] = ok ? __expf(ev) * inv[h] : 0.f;
        }
        s_j[w][lane] = jv;
        *(float4*)&s_af[w][lane][0] = make_float4(al[0], al[1], al[2], al[3]);
        int cnt = end - base; if (cnt > 64) cnt = 64;
        run_chunk(cnt);
    }

    if (active && lane < OUTC) {
        float v = acc0 * 0.25f + bias[lane] + skip[node * OUTC + lane];
        outp[node * OUTC + lane] = v;
    }
}

// ---------------------------------------------------------------------------
extern "C" void kernel_launch(void* const* d_in, const int* in_sizes, int n_in,
                              void* d_out, int out_size, void* d_ws, size_t ws_size,
                              hipStream_t stream) {
    const float* x        = (const float*)d_in[0];
    const int*   ei       = (const int*)d_in[1];
    const float* lin_w0   = (const float*)d_in[2];
    const float* att_src0 = (const float*)d_in[3];
    const float* att_dst0 = (const float*)d_in[4];
    const float* bias0    = (const float*)d_in[5];
    const float* skip_w0  = (const float*)d_in[6];
    const float* skip_b0  = (const float*)d_in[7];
    const float* lin_w1   = (const float*)d_in[8];
    const float* att_src1 = (const float*)d_in[9];
    const float* att_dst1 = (const float*)d_in[10];
    const float* bias1    = (const float*)d_in[11];
    const float* skip_w1  = (const float*)d_in[12];
    const float* skip_b1  = (const float*)d_in[13];
    const float* lin_w2   = (const float*)d_in[14];
    const float* att_src2 = (const float*)d_in[15];
    const float* att_dst2 = (const float*)d_in[16];
    const float* bias2    = (const float*)d_in[17];
    const float* skip_w2  = (const float*)d_in[18];
    const float* skip_b2  = (const float*)d_in[19];
    float* out = (float*)d_out;

    const int N = in_sizes[0] / KD;       // 50000
    const int E = in_sizes[1] / 2;        // 800000
    const int ET_ = E + N;                // with self loops

    char* ws = (char*)d_ws;
    size_t off = 0;
    auto alloc = [&](size_t bytes) -> void* {
        void* p = ws + off;
        off = (off + bytes + 255) & ~(size_t)255;
        return p;
    };
    void*   xh      = alloc((size_t)N * HC * 2 + 256);      // L0/1: bf16 128/row; L2: fp8 192B/row
    __bf16* buf_bf  = (__bf16*)alloc((size_t)N * HC * 2);   // ELU layer output (bf16)
    void*   skipbuf = alloc((size_t)N * HC * 4);            // skip: bf16 L0/1, fp32 L2
    float* a_src    = (float*)alloc((size_t)N * 4 * 4);
    float* a_dst    = (float*)alloc((size_t)N * 4 * 4);
    int* deg        = (int*)alloc((size_t)N * 4);
    int* row_ptr    = (int*)alloc((size_t)N * 4);
    int* fill       = (int*)alloc((size_t)N * 4);
    int* col        = (int*)alloc((size_t)ET_ * 4);
    int* counter    = (int*)alloc(256);
    __bf16* Bt      = (__bf16*)alloc((size_t)3 * 256 * 128 * 2);  // prepped weights

    // ---- weight prep (no deps; overlaps CSR build) ----
    prep_w_kernel<<<384, 256, 0, stream>>>(lin_w0, skip_w0, lin_w1, skip_w1,
                                           lin_w2, skip_w2, Bt);

    // ---- CSR build (dst-sorted adjacency, self-loops included) ----
    hipMemsetAsync(deg, 0, (size_t)N * 4, stream);
    hipMemsetAsync(counter, 0, 4, stream);
    int rngsz = (N + NPART - 1) / NPART;                 // 6250
    int cblocks = ((E + EPB - 1) / EPB) * NPART;         // 391 * 8
    count_kernel<<<cblocks, 256, 0, stream>>>(ei + E, deg, E, rngsz);
    scan_base_kernel<<<(N + 255) / 256, 256, 0, stream>>>(deg, counter, row_ptr, fill, col, N);
    fill_kernel<<<cblocks, 256, 0, stream>>>(ei, fill, col, E, rngsz);

    dim3 blk(256);
    int mblocks = (N + 63) / 64;            // BM=64
    int wave_blocks = (N + 3) / 4;          // one wave per node (agg1)
    int grp_blocks = (N + 15) / 16;         // 16 nodes/block (agg0)
    int att_blocks = (N * 16 + 255) / 256;  // 16 threads per node

    // ---- layer 0 (A = fp32 x, converted in staging; skip bf16) ----
    gemm_fused_kernel<float, __bf16, 2, 2, 0><<<mblocks, blk, 0, stream>>>(
        x, Bt, xh, HC, HC, skip_b0, (__bf16*)skipbuf, HC, N);
    att_kernel<<<att_blocks, blk, 0, stream>>>((const __bf16*)xh, att_src0, att_dst0,
                                               a_src, a_dst, N);
    agg0_kernel<<<grp_blocks, blk, 0, stream>>>((const uint4*)xh, a_src, a_dst,
                                                (const uint4*)skipbuf, bias0,
                                                row_ptr, deg, col, (uint4*)buf_bf, N);
    // ---- layer 1 (skip bf16) ----
    gemm_fused_kernel<__bf16, __bf16, 2, 2, 0><<<mblocks, blk, 0, stream>>>(
        buf_bf, Bt + 32768, xh, HC, HC, skip_b1, (__bf16*)skipbuf, HC, N);
    att_kernel<<<att_blocks, blk, 0, stream>>>((const __bf16*)xh, att_src1, att_dst1,
                                               a_src, a_dst, N);
    agg0_kernel<<<grp_blocks, blk, 0, stream>>>((const uint4*)xh, a_src, a_dst,
                                                (const uint4*)skipbuf, bias1,
                                                row_ptr, deg, col, (uint4*)buf_bf, N);
    // ---- layer 2 (xh fp8 e4m3, head-interleaved, 192 B rows; skip fp32) ----
    gemm_fused_kernel<__bf16, float, 3, 1, 1><<<mblocks, blk, 0, stream>>>(
        buf_bf, Bt + 65536, xh, NF2, NF2PB, skip_b2, (float*)skipbuf, OUTC, N);
    att2_kernel<<<wave_blocks, blk, 0, stream>>>((const unsigned char*)xh, att_src2,
                                                 att_dst2, a_src, a_dst, N);
    agg1_kernel<<<wave_blocks, blk, 0, stream>>>((const unsigned int*)xh, a_src, a_dst,
                                                 (const float*)skipbuf, bias2,
                                                 row_ptr, deg, col, out, N);
}